// Round 3
// baseline (11335.814 us; speedup 1.0000x reference)
//
#include <hip/hip_runtime.h>
#include <math.h>

#define VSZ 32000
#define EDIM 128
#define HDIM 256
#define BSZ 256
#define SLEN 256
#define ANUM 8
#define SALEN 32
#define G3 768
#define TB 16            // sequences per block (one M-tile)
#define PADW 392         // xh row length in shorts (384 + 8 pad)

// workspace layout
// WB: split-bf16 weight fragments: 4 enc x 12 kk x 4 wave x 12 tile x 2 (hi,lo) x 512 shorts
#define WB_SHORTS (4 * 12 * 4 * 12 * 2 * 512)   // 2,359,296 shorts = 4,718,592 B
#define OFF_HWT   (WB_SHORTS / 2)               // float offset = 1,179,648
#define HWT_SIZE  (1024 * HDIM)
#define OFF_STATE (OFF_HWT + HWT_SIZE)
#define OFF_ACT   (OFF_STATE + BSZ * G3)

typedef __attribute__((ext_vector_type(8))) short bf16x8;
typedef __attribute__((ext_vector_type(4))) float f32x4;

__device__ __forceinline__ unsigned short bf16_rne(float f) {
    unsigned int u = __builtin_bit_cast(unsigned int, f);
    unsigned int r = (u + 0x7FFFu + ((u >> 16) & 1u)) >> 16;
    return (unsigned short)r;
}
__device__ __forceinline__ float bf16_to_f32(unsigned short h) {
    unsigned int u = ((unsigned int)h) << 16;
    return __builtin_bit_cast(float, u);
}

// Build split-bf16 weight fragments in MFMA B-operand order.
// Fragment element: lane l, elem j -> B[k = 32*kk + 8*(l>>4) + j][n = 16*c + (l&15)]
//   = W[row = 256*g3 + 16*c + (l&15)][k], c = 4*ci + w, tl = ci*3 + g3
__global__ void prep_frag(const float* __restrict__ Wih, const float* __restrict__ Whh,
                          unsigned short* __restrict__ WB) {
    int idx = blockIdx.x * 256 + threadIdx.x;      // < 1,179,648
    int j = idx & 7;
    int l = (idx >> 3) & 63;
    int rest = idx >> 9;                            // (((enc*12+kk)*4+w)*12+tl)
    int tl = rest % 12; rest /= 12;
    int w  = rest & 3;  rest >>= 2;
    int kk = rest % 12;
    int enc = rest / 12;
    int ci = tl / 3, g3 = tl % 3;
    int c = 4 * ci + w;
    int row = 256 * g3 + 16 * c + (l & 15);
    int kloc = 8 * (l >> 4) + j;
    float v;
    if (kk < 4) v = Wih[(enc * G3 + row) * EDIM + 32 * kk + kloc];
    else        v = Whh[(enc * G3 + row) * HDIM + 32 * (kk - 4) + kloc];
    unsigned short hi = bf16_rne(v);
    unsigned short lo = bf16_rne(v - bf16_to_f32(hi));
    int base = ((((enc * 12 + kk) * 4 + w) * 12 + tl) * 2) * 512 + l * 8 + j;
    WB[base] = hi;
    WB[base + 512] = lo;
}

__global__ void prep_hwt(const float* __restrict__ hW, float* __restrict__ hWT) {
    int idx = blockIdx.x * 256 + threadIdx.x;
    if (idx >= HWT_SIZE) return;
    int k = idx >> 8;
    int j = idx & 255;
    hWT[idx] = hW[j * 1024 + k];
}

// 256 threads = 4 waves. Wave wv owns channel tiles c = 4*ci + wv (ci=0..3),
// i.e. channels j = 64*ci + 16*wv + (l&15). Each wave has r,z,n for ITS channels.
__global__ void __launch_bounds__(256)
gru_mfma(const int* __restrict__ obs_t, const int* __restrict__ obs_l,
         const int* __restrict__ look_t, const int* __restrict__ look_l,
         const int* __restrict__ inv_t, const int* __restrict__ inv_l,
         const int* __restrict__ act_t, const int* __restrict__ act_l,
         const float* __restrict__ emb, const float* __restrict__ bih,
         const float* __restrict__ bhh, const unsigned short* __restrict__ WB,
         float* __restrict__ state, float* __restrict__ act_out) {
    int bid = blockIdx.x;
    int enc, tile, S;
    const int* toks;
    const int* lens;
    if (bid < 48) {
        enc = bid >> 4; tile = bid & 15; S = SLEN;
        toks = (enc == 0) ? obs_t : (enc == 1) ? look_t : inv_t;
        lens = (enc == 0) ? obs_l : (enc == 1) ? look_l : inv_l;
    } else {
        enc = 3; tile = bid - 48; S = SALEN;
        toks = act_t; lens = act_l;
    }
    const int tid = threadIdx.x;
    const int l  = tid & 63;
    const int wv = tid >> 6;
    const int lr = l & 15;     // frag row/col index (m for A, n for B/C-col)
    const int lg = l >> 4;     // k-group / C row-group

    __shared__ __align__(16) unsigned short xh_hi[TB][PADW];
    __shared__ __align__(16) unsigned short xh_lo[TB][PADW];

    // init h region [128,384) to zero
    for (int i = tid; i < TB * 256; i += 256) {
        int m = i >> 8, c2 = i & 255;
        xh_hi[m][EDIM + c2] = 0;
        xh_lo[m][EDIM + c2] = 0;
    }

    // lengths
    int maxlen = 1;
    for (int s = 0; s < TB; ++s) {
        int L = lens[tile * TB + s];
        if (L < 1) L = 1;
        if (L > maxlen) maxlen = L;
    }
    int lenm[4];
#pragma unroll
    for (int i = 0; i < 4; ++i) {
        int L = lens[tile * TB + 4 * lg + i];
        lenm[i] = (L < 1) ? 1 : L;
    }

    // biases: col of C = lr -> channel j = 64*ci + 16*wv + lr
    float bR[4], bZ[4], bIN[4], bHN[4];
#pragma unroll
    for (int ci = 0; ci < 4; ++ci) {
        int j = 64 * ci + 16 * wv + lr;
        bR[ci]  = bih[enc * G3 + j] + bhh[enc * G3 + j];
        bZ[ci]  = bih[enc * G3 + 256 + j] + bhh[enc * G3 + 256 + j];
        bIN[ci] = bih[enc * G3 + 512 + j];
        bHN[ci] = bhh[enc * G3 + 512 + j];
    }

    float hO[4][4];
#pragma unroll
    for (int ci = 0; ci < 4; ++ci)
#pragma unroll
        for (int i = 0; i < 4; ++i) hO[ci][i] = 0.f;

    // stage x for step t: 16 threads per seq row, 8 floats each
    auto stage = [&](int tt) {
        int m = tid >> 4, g = tid & 15;
        int tok = toks[(tile * TB + m) * S + tt];
        const float* e = emb + (size_t)tok * EDIM + g * 8;
        float4 v0 = *(const float4*)e;
        float4 v1 = *(const float4*)(e + 4);
        float vv[8] = {v0.x, v0.y, v0.z, v0.w, v1.x, v1.y, v1.z, v1.w};
        bf16x8 H, Lo;
#pragma unroll
        for (int q = 0; q < 8; ++q) {
            unsigned short h16 = bf16_rne(vv[q]);
            H[q]  = (short)h16;
            Lo[q] = (short)bf16_rne(vv[q] - bf16_to_f32(h16));
        }
        *(bf16x8*)(&xh_hi[m][g * 8]) = H;
        *(bf16x8*)(&xh_lo[m][g * 8]) = Lo;
    };

    stage(0);
    __syncthreads();

    const unsigned short* WBe = WB + ((size_t)enc * 12 * 4) * 12288;

    for (int t = 0; t < maxlen; ++t) {
        f32x4 aR[4], aZ[4], aNX[4], aNH[4];
#pragma unroll
        for (int ci = 0; ci < 4; ++ci) {
            aR[ci]  = (f32x4){bR[ci], bR[ci], bR[ci], bR[ci]};
            aZ[ci]  = (f32x4){bZ[ci], bZ[ci], bZ[ci], bZ[ci]};
            aNX[ci] = (f32x4){bIN[ci], bIN[ci], bIN[ci], bIN[ci]};
            aNH[ci] = (f32x4){bHN[ci], bHN[ci], bHN[ci], bHN[ci]};
        }

        // x-part: kk = 0..3, n-gate -> aNX
        for (int kk = 0; kk < 4; ++kk) {
            bf16x8 Ahi = *(const bf16x8*)(&xh_hi[lr][32 * kk + 8 * lg]);
            bf16x8 Alo = *(const bf16x8*)(&xh_lo[lr][32 * kk + 8 * lg]);
            const unsigned short* wb = WBe + ((size_t)(kk * 4 + wv)) * 12288 + l * 8;
#pragma unroll
            for (int h2 = 0; h2 < 2; ++h2) {
                bf16x8 Bh[6], Bl[6];
#pragma unroll
                for (int u = 0; u < 6; ++u) {
                    Bh[u] = *(const bf16x8*)(wb + (h2 * 6 + u) * 1024);
                    Bl[u] = *(const bf16x8*)(wb + (h2 * 6 + u) * 1024 + 512);
                }
#pragma unroll
                for (int cc = 0; cc < 2; ++cc) {
                    int ci = h2 * 2 + cc;
                    aR[ci]  = __builtin_amdgcn_mfma_f32_16x16x32_bf16(Ahi, Bh[cc*3+0], aR[ci], 0, 0, 0);
                    aR[ci]  = __builtin_amdgcn_mfma_f32_16x16x32_bf16(Ahi, Bl[cc*3+0], aR[ci], 0, 0, 0);
                    aR[ci]  = __builtin_amdgcn_mfma_f32_16x16x32_bf16(Alo, Bh[cc*3+0], aR[ci], 0, 0, 0);
                    aZ[ci]  = __builtin_amdgcn_mfma_f32_16x16x32_bf16(Ahi, Bh[cc*3+1], aZ[ci], 0, 0, 0);
                    aZ[ci]  = __builtin_amdgcn_mfma_f32_16x16x32_bf16(Ahi, Bl[cc*3+1], aZ[ci], 0, 0, 0);
                    aZ[ci]  = __builtin_amdgcn_mfma_f32_16x16x32_bf16(Alo, Bh[cc*3+1], aZ[ci], 0, 0, 0);
                    aNX[ci] = __builtin_amdgcn_mfma_f32_16x16x32_bf16(Ahi, Bh[cc*3+2], aNX[ci], 0, 0, 0);
                    aNX[ci] = __builtin_amdgcn_mfma_f32_16x16x32_bf16(Ahi, Bl[cc*3+2], aNX[ci], 0, 0, 0);
                    aNX[ci] = __builtin_amdgcn_mfma_f32_16x16x32_bf16(Alo, Bh[cc*3+2], aNX[ci], 0, 0, 0);
                }
            }
        }
        // h-part: kk = 4..11, n-gate -> aNH
        for (int kh = 0; kh < 8; ++kh) {
            bf16x8 Ahi = *(const bf16x8*)(&xh_hi[lr][EDIM + 32 * kh + 8 * lg]);
            bf16x8 Alo = *(const bf16x8*)(&xh_lo[lr][EDIM + 32 * kh + 8 * lg]);
            const unsigned short* wb = WBe + ((size_t)((kh + 4) * 4 + wv)) * 12288 + l * 8;
#pragma unroll
            for (int h2 = 0; h2 < 2; ++h2) {
                bf16x8 Bh[6], Bl[6];
#pragma unroll
                for (int u = 0; u < 6; ++u) {
                    Bh[u] = *(const bf16x8*)(wb + (h2 * 6 + u) * 1024);
                    Bl[u] = *(const bf16x8*)(wb + (h2 * 6 + u) * 1024 + 512);
                }
#pragma unroll
                for (int cc = 0; cc < 2; ++cc) {
                    int ci = h2 * 2 + cc;
                    aR[ci]  = __builtin_amdgcn_mfma_f32_16x16x32_bf16(Ahi, Bh[cc*3+0], aR[ci], 0, 0, 0);
                    aR[ci]  = __builtin_amdgcn_mfma_f32_16x16x32_bf16(Ahi, Bl[cc*3+0], aR[ci], 0, 0, 0);
                    aR[ci]  = __builtin_amdgcn_mfma_f32_16x16x32_bf16(Alo, Bh[cc*3+0], aR[ci], 0, 0, 0);
                    aZ[ci]  = __builtin_amdgcn_mfma_f32_16x16x32_bf16(Ahi, Bh[cc*3+1], aZ[ci], 0, 0, 0);
                    aZ[ci]  = __builtin_amdgcn_mfma_f32_16x16x32_bf16(Ahi, Bl[cc*3+1], aZ[ci], 0, 0, 0);
                    aZ[ci]  = __builtin_amdgcn_mfma_f32_16x16x32_bf16(Alo, Bh[cc*3+1], aZ[ci], 0, 0, 0);
                    aNH[ci] = __builtin_amdgcn_mfma_f32_16x16x32_bf16(Ahi, Bh[cc*3+2], aNH[ci], 0, 0, 0);
                    aNH[ci] = __builtin_amdgcn_mfma_f32_16x16x32_bf16(Ahi, Bl[cc*3+2], aNH[ci], 0, 0, 0);
                    aNH[ci] = __builtin_amdgcn_mfma_f32_16x16x32_bf16(Alo, Bh[cc*3+2], aNH[ci], 0, 0, 0);
                }
            }
        }

        __syncthreads();   // all xh reads done before h overwrite

        // gates + h update; C layout: row m = 4*lg + i, col = lr
#pragma unroll
        for (int ci = 0; ci < 4; ++ci) {
            int j = 64 * ci + 16 * wv + lr;
#pragma unroll
            for (int i = 0; i < 4; ++i) {
                int m = 4 * lg + i;
                float r = 1.f / (1.f + expf(-aR[ci][i]));
                float z = 1.f / (1.f + expf(-aZ[ci][i]));
                float n = tanhf(aNX[ci][i] + r * aNH[ci][i]);
                float hv = (1.f - z) * n + z * hO[ci][i];
                hv = (t < lenm[i]) ? hv : hO[ci][i];
                hO[ci][i] = hv;
                unsigned short h16 = bf16_rne(hv);
                xh_hi[m][EDIM + j] = h16;
                xh_lo[m][EDIM + j] = bf16_rne(hv - bf16_to_f32(h16));
            }
        }
        if (t + 1 < maxlen) stage(t + 1);
        __syncthreads();
    }

    // write outputs: lane owns (m = 4*lg+i, j = 64*ci+16*wv+lr)
#pragma unroll
    for (int ci = 0; ci < 4; ++ci) {
        int j = 64 * ci + 16 * wv + lr;
#pragma unroll
        for (int i = 0; i < 4; ++i) {
            int sg = tile * TB + 4 * lg + i;
            if (enc < 3) state[sg * G3 + enc * HDIM + j] = hO[ci][i];
            else         act_out[sg * HDIM + j] = hO[ci][i];
        }
    }
}

__global__ void __launch_bounds__(256)
mlp_kernel(const float* __restrict__ state, const float* __restrict__ act_out,
           const float* __restrict__ hWT, const float* __restrict__ hb,
           const float* __restrict__ sW, const float* __restrict__ sb,
           float* __restrict__ q) {
    int b = blockIdx.x;
    int j = threadIdx.x;
    __shared__ float st[G3];
    __shared__ float ab[ANUM][HDIM];
#pragma unroll
    for (int i = 0; i < 3; ++i) st[i * 256 + j] = state[b * G3 + i * 256 + j];
#pragma unroll
    for (int i = 0; i < ANUM; ++i) ab[i][j] = act_out[(b * ANUM + i) * HDIM + j];
    __syncthreads();

    float accS = 0.f;
#pragma unroll 4
    for (int k = 0; k < G3; ++k) accS += st[k] * hWT[k * HDIM + j];

    float accA[ANUM];
#pragma unroll
    for (int i = 0; i < ANUM; ++i) accA[i] = 0.f;
    for (int k = 0; k < HDIM; ++k) {
        float w = hWT[(G3 + k) * HDIM + j];
#pragma unroll
        for (int i = 0; i < ANUM; ++i) accA[i] += ab[i][k] * w;
    }

    float base = hb[j] + accS;
    float p[ANUM];
#pragma unroll
    for (int i = 0; i < ANUM; ++i) {
        float zz = base + accA[i];
        zz = zz > 0.f ? zz : 0.f;
        p[i] = zz * sW[j];
    }

    __shared__ float wsum[ANUM][4];
#pragma unroll
    for (int i = 0; i < ANUM; ++i) {
        float v = p[i];
        for (int off = 32; off >= 1; off >>= 1) v += __shfl_down(v, off, 64);
        if ((j & 63) == 0) wsum[i][j >> 6] = v;
    }
    __syncthreads();
    if (j < ANUM) q[b * ANUM + j] = wsum[j][0] + wsum[j][1] + wsum[j][2] + wsum[j][3] + sb[0];
}

extern "C" void kernel_launch(void* const* d_in, const int* in_sizes, int n_in,
                              void* d_out, int out_size, void* d_ws, size_t ws_size,
                              hipStream_t stream) {
    const int* obs_t  = (const int*)d_in[0];
    const int* obs_l  = (const int*)d_in[1];
    const int* look_t = (const int*)d_in[2];
    const int* look_l = (const int*)d_in[3];
    const int* inv_t  = (const int*)d_in[4];
    const int* inv_l  = (const int*)d_in[5];
    const int* act_t  = (const int*)d_in[6];
    const int* act_l  = (const int*)d_in[7];
    const float* emb  = (const float*)d_in[8];
    const float* Wih  = (const float*)d_in[9];
    const float* Whh  = (const float*)d_in[10];
    const float* bih  = (const float*)d_in[11];
    const float* bhh  = (const float*)d_in[12];
    const float* hW   = (const float*)d_in[13];
    const float* hb   = (const float*)d_in[14];
    const float* sW   = (const float*)d_in[15];
    const float* sb   = (const float*)d_in[16];

    float* ws    = (float*)d_ws;
    unsigned short* WB = (unsigned short*)d_ws;
    float* hWT   = ws + OFF_HWT;
    float* state = ws + OFF_STATE;
    float* act_o = ws + OFF_ACT;

    prep_frag<<<(WB_SHORTS / 2 + 255) / 256, 256, 0, stream>>>(Wih, Whh, WB);
    prep_hwt<<<(HWT_SIZE + 255) / 256, 256, 0, stream>>>(hW, hWT);
    gru_mfma<<<176, 256, 0, stream>>>(obs_t, obs_l, look_t, look_l, inv_t, inv_l,
                                      act_t, act_l, emb, bih, bhh, WB, state, act_o);
    mlp_kernel<<<256, 256, 0, stream>>>(state, act_o, hWT, hb, sW, sb, (float*)d_out);
}

// Round 4
// 3049.199 us; speedup vs baseline: 3.7176x; 3.7176x over previous
//
#include <hip/hip_runtime.h>
#include <math.h>

#define VSZ 32000
#define EDIM 128
#define HDIM 256
#define BSZ 256
#define SLEN 256
#define ANUM 8
#define SALEN 32
#define G3 768
#define TB 16            // sequences per block (one M-tile)
#define PADW 392         // xh row length in shorts (384 + 8 pad)

// WB: split-bf16 weight fragments: [enc4][kk12][wv8][slot6][hi/lo 2][512 shorts]
#define WB_SHORTS (4 * 12 * 8 * 6 * 2 * 512)    // 2,359,296 shorts = 4.72 MB
#define KK_STRIDE (8 * 6 * 2 * 512)             // 49152 shorts per kk
#define OFF_HWT   (WB_SHORTS / 2)               // float offset
#define HWT_SIZE  (1024 * HDIM)
#define OFF_STATE (OFF_HWT + HWT_SIZE)
#define OFF_ACT   (OFF_STATE + BSZ * G3)

typedef __attribute__((ext_vector_type(8))) short bf16x8;
typedef __attribute__((ext_vector_type(4))) short bf16x4;
typedef __attribute__((ext_vector_type(4))) float f32x4;

__device__ __forceinline__ unsigned short bf16_rne(float f) {
    unsigned int u = __builtin_bit_cast(unsigned int, f);
    unsigned int r = (u + 0x7FFFu + ((u >> 16) & 1u)) >> 16;
    return (unsigned short)r;
}
__device__ __forceinline__ float bf16_to_f32(unsigned short h) {
    unsigned int u = ((unsigned int)h) << 16;
    return __builtin_bit_cast(float, u);
}

// B-fragment: lane l elem q -> B[k = 32*kk + 8*(l>>4) + q][n], n = 256*g3 + 16*(wv+8*cc2) + (l&15)
__global__ void prep_frag(const float* __restrict__ Wih, const float* __restrict__ Whh,
                          unsigned short* __restrict__ WB) {
    int idx = blockIdx.x * 256 + threadIdx.x;      // < 1,179,648 (hi elements)
    int q = idx & 7;
    int l = (idx >> 3) & 63;
    int rest = idx >> 9;
    int slot = rest % 6; rest /= 6;                // slot = cc2*3 + g3
    int wv = rest & 7;   rest >>= 3;
    int kk = rest % 12;
    int enc = rest / 12;
    int cc2 = slot / 3, g3 = slot % 3;
    int row = 256 * g3 + 16 * (wv + 8 * cc2) + (l & 15);
    int kloc = 8 * (l >> 4) + q;
    float v;
    if (kk < 4) v = Wih[(enc * G3 + row) * EDIM + 32 * kk + kloc];
    else        v = Whh[(enc * G3 + row) * HDIM + 32 * (kk - 4) + kloc];
    unsigned short hi = bf16_rne(v);
    unsigned short lo = bf16_rne(v - bf16_to_f32(hi));
    size_t base = ((((size_t)(enc * 12 + kk) * 8 + wv) * 6 + slot) * 2) * 512 + l * 8 + q;
    WB[base] = hi;
    WB[base + 512] = lo;
}

__global__ void prep_hwt(const float* __restrict__ hW, float* __restrict__ hWT) {
    int idx = blockIdx.x * 256 + threadIdx.x;
    if (idx >= HWT_SIZE) return;
    int k = idx >> 8;
    int j = idx & 255;
    hWT[idx] = hW[j * 1024 + k];
}

// 512 threads = 8 waves. Wave wv owns channel-tiles cc in {wv, wv+8},
// i.e. channels j = 16*wv + 128*cc2 + lr. All 3 gates for those channels.
__global__ void __launch_bounds__(512, 2)
gru_mfma(const int* __restrict__ obs_t, const int* __restrict__ obs_l,
         const int* __restrict__ look_t, const int* __restrict__ look_l,
         const int* __restrict__ inv_t, const int* __restrict__ inv_l,
         const int* __restrict__ act_t, const int* __restrict__ act_l,
         const float* __restrict__ emb, const float* __restrict__ bih,
         const float* __restrict__ bhh, const unsigned short* __restrict__ WB,
         float* __restrict__ state, float* __restrict__ act_out) {
    const int bid = blockIdx.x;
    // XCD-aware mapping: bid%8 ~ XCD. XCD pair {0,1}->enc0, {2,3}->enc1,
    // {4,5}->enc2; act fills XCDs 6,7 plus the leftover slots everywhere.
    const int x = bid & 7, rr = bid >> 3;   // grid = 176 -> rr in 0..21
    int enc, tile, S;
    const int* toks;
    const int* lens;
    if (x < 6 && rr < 8) {
        enc = x >> 1; tile = (x & 1) * 8 + rr; S = SLEN;
        toks = (enc == 0) ? obs_t : (enc == 1) ? look_t : inv_t;
        lens = (enc == 0) ? obs_l : (enc == 1) ? look_l : inv_l;
    } else {
        enc = 3; S = SALEN;
        tile = (x >= 6) ? (rr * 2 + (x - 6)) : (44 + (rr - 8) * 6 + x);
        toks = act_t; lens = act_l;
    }
    const int tid = threadIdx.x;
    const int l  = tid & 63;
    const int wv = tid >> 6;     // 0..7
    const int lr = l & 15;
    const int lg = l >> 4;

    __shared__ __align__(16) unsigned short xh_hi[TB][PADW];
    __shared__ __align__(16) unsigned short xh_lo[TB][PADW];
    __shared__ float pad_force[14336];   // 56KB: forces 1 block/CU (82KB total LDS)

    // init h region [128,384) to zero: 512 threads x 8 shorts
    {
        int m = tid >> 5, c = tid & 31;
        for (int q = 0; q < 8; ++q) {
            xh_hi[m][EDIM + 8 * c + q] = 0;
            xh_lo[m][EDIM + 8 * c + q] = 0;
        }
    }

    // lengths
    int maxlen = 1;
    for (int s = 0; s < TB; ++s) {
        int L = lens[tile * TB + s];
        if (L < 1) L = 1;
        if (L > maxlen) maxlen = L;
    }
    if (maxlen == -1) pad_force[tid] = 1.f;   // never true; keeps pad allocated
    int lenm[4];
#pragma unroll
    for (int i = 0; i < 4; ++i) {
        int L = lens[tile * TB + 4 * lg + i];
        lenm[i] = (L < 1) ? 1 : L;
    }

    // biases for owned channels j = 16*wv + 128*cc2 + lr
    float bR[2], bZ[2], bIN[2], bHN[2];
#pragma unroll
    for (int c2 = 0; c2 < 2; ++c2) {
        int j = 16 * wv + 128 * c2 + lr;
        bR[c2]  = bih[enc * G3 + j] + bhh[enc * G3 + j];
        bZ[c2]  = bih[enc * G3 + 256 + j] + bhh[enc * G3 + 256 + j];
        bIN[c2] = bih[enc * G3 + 512 + j];
        bHN[c2] = bhh[enc * G3 + 512 + j];
    }

    float hO[2][4];
#pragma unroll
    for (int c2 = 0; c2 < 2; ++c2)
#pragma unroll
        for (int i = 0; i < 4; ++i) hO[c2][i] = 0.f;

    // stage x_t: 512 threads, each 4 floats of one seq row
    auto stage = [&](int tt) {
        int m = tid >> 5, g = tid & 31;
        int tok = toks[(tile * TB + m) * S + tt];
        const float4 v = *(const float4*)(emb + (size_t)tok * EDIM + g * 4);
        float vv[4] = {v.x, v.y, v.z, v.w};
        bf16x4 H, Lo;
#pragma unroll
        for (int q = 0; q < 4; ++q) {
            unsigned short h16 = bf16_rne(vv[q]);
            H[q]  = (short)h16;
            Lo[q] = (short)bf16_rne(vv[q] - bf16_to_f32(h16));
        }
        *(bf16x4*)(&xh_hi[m][g * 4]) = H;
        *(bf16x4*)(&xh_lo[m][g * 4]) = Lo;
    };

    stage(0);
    __syncthreads();

    const unsigned short* WBw = WB + (size_t)enc * (12 * KK_STRIDE)
                                   + wv * (6 * 2 * 512) + l * 8;

    for (int t = 0; t < maxlen; ++t) {
        f32x4 aR[2], aZ[2], aNX[2], aNH[2];
#pragma unroll
        for (int c2 = 0; c2 < 2; ++c2) {
            aR[c2]  = (f32x4){bR[c2], bR[c2], bR[c2], bR[c2]};
            aZ[c2]  = (f32x4){bZ[c2], bZ[c2], bZ[c2], bZ[c2]};
            aNX[c2] = (f32x4){bIN[c2], bIN[c2], bIN[c2], bIN[c2]};
            aNH[c2] = (f32x4){bHN[c2], bHN[c2], bHN[c2], bHN[c2]};
        }

#pragma unroll 2
        for (int kk = 0; kk < 12; ++kk) {
            const int off = (kk < 4) ? 32 * kk : EDIM + 32 * (kk - 4);
            bf16x8 Ahi = *(const bf16x8*)(&xh_hi[lr][off + 8 * lg]);
            bf16x8 Alo = *(const bf16x8*)(&xh_lo[lr][off + 8 * lg]);
            const unsigned short* wb = WBw + (size_t)kk * KK_STRIDE;
#pragma unroll
            for (int c2 = 0; c2 < 2; ++c2) {
                bf16x8 BhR = *(const bf16x8*)(wb + (c2 * 3 + 0) * 1024);
                bf16x8 BlR = *(const bf16x8*)(wb + (c2 * 3 + 0) * 1024 + 512);
                bf16x8 BhZ = *(const bf16x8*)(wb + (c2 * 3 + 1) * 1024);
                bf16x8 BlZ = *(const bf16x8*)(wb + (c2 * 3 + 1) * 1024 + 512);
                bf16x8 BhN = *(const bf16x8*)(wb + (c2 * 3 + 2) * 1024);
                bf16x8 BlN = *(const bf16x8*)(wb + (c2 * 3 + 2) * 1024 + 512);
                aR[c2] = __builtin_amdgcn_mfma_f32_16x16x32_bf16(Ahi, BhR, aR[c2], 0, 0, 0);
                aR[c2] = __builtin_amdgcn_mfma_f32_16x16x32_bf16(Ahi, BlR, aR[c2], 0, 0, 0);
                aR[c2] = __builtin_amdgcn_mfma_f32_16x16x32_bf16(Alo, BhR, aR[c2], 0, 0, 0);
                aZ[c2] = __builtin_amdgcn_mfma_f32_16x16x32_bf16(Ahi, BhZ, aZ[c2], 0, 0, 0);
                aZ[c2] = __builtin_amdgcn_mfma_f32_16x16x32_bf16(Ahi, BlZ, aZ[c2], 0, 0, 0);
                aZ[c2] = __builtin_amdgcn_mfma_f32_16x16x32_bf16(Alo, BhZ, aZ[c2], 0, 0, 0);
                if (kk < 4) {
                    aNX[c2] = __builtin_amdgcn_mfma_f32_16x16x32_bf16(Ahi, BhN, aNX[c2], 0, 0, 0);
                    aNX[c2] = __builtin_amdgcn_mfma_f32_16x16x32_bf16(Ahi, BlN, aNX[c2], 0, 0, 0);
                    aNX[c2] = __builtin_amdgcn_mfma_f32_16x16x32_bf16(Alo, BhN, aNX[c2], 0, 0, 0);
                } else {
                    aNH[c2] = __builtin_amdgcn_mfma_f32_16x16x32_bf16(Ahi, BhN, aNH[c2], 0, 0, 0);
                    aNH[c2] = __builtin_amdgcn_mfma_f32_16x16x32_bf16(Ahi, BlN, aNH[c2], 0, 0, 0);
                    aNH[c2] = __builtin_amdgcn_mfma_f32_16x16x32_bf16(Alo, BhN, aNH[c2], 0, 0, 0);
                }
            }
        }

        __syncthreads();   // all xh reads of this step done

        // gates + h update; C layout: row m = 4*lg + i, col = lr
#pragma unroll
        for (int c2 = 0; c2 < 2; ++c2) {
            int j = 16 * wv + 128 * c2 + lr;
#pragma unroll
            for (int i = 0; i < 4; ++i) {
                int m = 4 * lg + i;
                float r = 1.f / (1.f + expf(-aR[c2][i]));
                float z = 1.f / (1.f + expf(-aZ[c2][i]));
                float n = tanhf(aNX[c2][i] + r * aNH[c2][i]);
                float hv = (1.f - z) * n + z * hO[c2][i];
                hv = (t < lenm[i]) ? hv : hO[c2][i];
                hO[c2][i] = hv;
                unsigned short h16 = bf16_rne(hv);
                xh_hi[m][EDIM + j] = h16;
                xh_lo[m][EDIM + j] = bf16_rne(hv - bf16_to_f32(h16));
            }
        }
        if (t + 1 < maxlen) stage(t + 1);
        __syncthreads();
    }

    // outputs: lane owns (m = 4*lg+i, j = 16*wv + 128*c2 + lr)
#pragma unroll
    for (int c2 = 0; c2 < 2; ++c2) {
        int j = 16 * wv + 128 * c2 + lr;
#pragma unroll
        for (int i = 0; i < 4; ++i) {
            int sg = tile * TB + 4 * lg + i;
            if (enc < 3) state[sg * G3 + enc * HDIM + j] = hO[c2][i];
            else         act_out[sg * HDIM + j] = hO[c2][i];
        }
    }
}

__global__ void __launch_bounds__(256)
mlp_kernel(const float* __restrict__ state, const float* __restrict__ act_out,
           const float* __restrict__ hWT, const float* __restrict__ hb,
           const float* __restrict__ sW, const float* __restrict__ sb,
           float* __restrict__ q) {
    int b = blockIdx.x;
    int j = threadIdx.x;
    __shared__ float st[G3];
    __shared__ float ab[ANUM][HDIM];
#pragma unroll
    for (int i = 0; i < 3; ++i) st[i * 256 + j] = state[b * G3 + i * 256 + j];
#pragma unroll
    for (int i = 0; i < ANUM; ++i) ab[i][j] = act_out[(b * ANUM + i) * HDIM + j];
    __syncthreads();

    float accS = 0.f;
#pragma unroll 4
    for (int k = 0; k < G3; ++k) accS += st[k] * hWT[k * HDIM + j];

    float accA[ANUM];
#pragma unroll
    for (int i = 0; i < ANUM; ++i) accA[i] = 0.f;
    for (int k = 0; k < HDIM; ++k) {
        float w = hWT[(G3 + k) * HDIM + j];
#pragma unroll
        for (int i = 0; i < ANUM; ++i) accA[i] += ab[i][k] * w;
    }

    float base = hb[j] + accS;
    float p[ANUM];
#pragma unroll
    for (int i = 0; i < ANUM; ++i) {
        float zz = base + accA[i];
        zz = zz > 0.f ? zz : 0.f;
        p[i] = zz * sW[j];
    }

    __shared__ float wsum[ANUM][4];
#pragma unroll
    for (int i = 0; i < ANUM; ++i) {
        float v = p[i];
        for (int off = 32; off >= 1; off >>= 1) v += __shfl_down(v, off, 64);
        if ((j & 63) == 0) wsum[i][j >> 6] = v;
    }
    __syncthreads();
    if (j < ANUM) q[b * ANUM + j] = wsum[j][0] + wsum[j][1] + wsum[j][2] + wsum[j][3] + sb[0];
}

extern "C" void kernel_launch(void* const* d_in, const int* in_sizes, int n_in,
                              void* d_out, int out_size, void* d_ws, size_t ws_size,
                              hipStream_t stream) {
    const int* obs_t  = (const int*)d_in[0];
    const int* obs_l  = (const int*)d_in[1];
    const int* look_t = (const int*)d_in[2];
    const int* look_l = (const int*)d_in[3];
    const int* inv_t  = (const int*)d_in[4];
    const int* inv_l  = (const int*)d_in[5];
    const int* act_t  = (const int*)d_in[6];
    const int* act_l  = (const int*)d_in[7];
    const float* emb  = (const float*)d_in[8];
    const float* Wih  = (const float*)d_in[9];
    const float* Whh  = (const float*)d_in[10];
    const float* bih  = (const float*)d_in[11];
    const float* bhh  = (const float*)d_in[12];
    const float* hW   = (const float*)d_in[13];
    const float* hb   = (const float*)d_in[14];
    const float* sW   = (const float*)d_in[15];
    const float* sb   = (const float*)d_in[16];

    float* ws    = (float*)d_ws;
    unsigned short* WB = (unsigned short*)d_ws;
    float* hWT   = ws + OFF_HWT;
    float* state = ws + OFF_STATE;
    float* act_o = ws + OFF_ACT;

    prep_frag<<<(WB_SHORTS / 2 + 255) / 256, 256, 0, stream>>>(Wih, Whh, WB);
    prep_hwt<<<(HWT_SIZE + 255) / 256, 256, 0, stream>>>(hW, hWT);
    gru_mfma<<<176, 512, 0, stream>>>(obs_t, obs_l, look_t, look_l, inv_t, inv_l,
                                      act_t, act_l, emb, bih, bhh, WB, state, act_o);
    mlp_kernel<<<256, 256, 0, stream>>>(state, act_o, hWT, hb, sW, sb, (float*)d_out);
}

// Round 5
// 3037.632 us; speedup vs baseline: 3.7318x; 1.0038x over previous
//
#include <hip/hip_runtime.h>
#include <math.h>

#define VSZ 32000
#define EDIM 128
#define HDIM 256
#define BSZ 256
#define SLEN 256
#define ANUM 8
#define SALEN 32
#define G3 768
#define TB 16            // sequences per block (one M-tile)
#define PADW 392         // xh row length in shorts (384 + 8 pad)

// WB: split-bf16 weight fragments: [enc4][kk12][wv8][slot6][hi/lo 2][512 shorts]
#define WB_SHORTS (4 * 12 * 8 * 6 * 2 * 512)    // 2,359,296 shorts = 4.72 MB
#define KK_STRIDE (8 * 6 * 2 * 512)             // 49152 shorts per kk
#define WV_STRIDE (6 * 2 * 512)                 // 6144 shorts per wv
#define OFF_HWT   (WB_SHORTS / 2)               // float offset
#define HWT_SIZE  (1024 * HDIM)
#define OFF_STATE (OFF_HWT + HWT_SIZE)
#define OFF_ACT   (OFF_STATE + BSZ * G3)
#define OFF_GI    (OFF_ACT + 2048 * HDIM)       // 2,162,688 floats
#define GI_FLOATS (3ull * 16 * 256 * 16 * 768)  // 150,994,944 floats (604 MB)
#define WS_NEED   (((unsigned long long)OFF_GI + GI_FLOATS) * 4ull)

typedef __attribute__((ext_vector_type(8))) short bf16x8;
typedef __attribute__((ext_vector_type(4))) short bf16x4;
typedef __attribute__((ext_vector_type(4))) float f32x4;

__device__ __forceinline__ unsigned short bf16_rne(float f) {
    unsigned int u = __builtin_bit_cast(unsigned int, f);
    unsigned int r = (u + 0x7FFFu + ((u >> 16) & 1u)) >> 16;
    return (unsigned short)r;
}
__device__ __forceinline__ float bf16_to_f32(unsigned short h) {
    unsigned int u = ((unsigned int)h) << 16;
    return __builtin_bit_cast(float, u);
}

// B-fragment: lane l elem q -> B[k = 32*kk + 8*(l>>4) + q][n], n = 256*g3 + 16*(wv+8*cc2) + (l&15)
__global__ void prep_frag(const float* __restrict__ Wih, const float* __restrict__ Whh,
                          unsigned short* __restrict__ WB) {
    int idx = blockIdx.x * 256 + threadIdx.x;      // < 1,179,648 (hi elements)
    int q = idx & 7;
    int l = (idx >> 3) & 63;
    int rest = idx >> 9;
    int slot = rest % 6; rest /= 6;                // slot = cc2*3 + g3
    int wv = rest & 7;   rest >>= 3;
    int kk = rest % 12;
    int enc = rest / 12;
    int cc2 = slot / 3, g3 = slot % 3;
    int row = 256 * g3 + 16 * (wv + 8 * cc2) + (l & 15);
    int kloc = 8 * (l >> 4) + q;
    float v;
    if (kk < 4) v = Wih[(enc * G3 + row) * EDIM + 32 * kk + kloc];
    else        v = Whh[(enc * G3 + row) * HDIM + 32 * (kk - 4) + kloc];
    unsigned short hi = bf16_rne(v);
    unsigned short lo = bf16_rne(v - bf16_to_f32(hi));
    size_t base = ((((size_t)(enc * 12 + kk) * 8 + wv) * 6 + slot) * 2) * 512 + l * 8 + q;
    WB[base] = hi;
    WB[base + 512] = lo;
}

__global__ void prep_hwt(const float* __restrict__ hW, float* __restrict__ hWT) {
    int idx = blockIdx.x * 256 + threadIdx.x;
    if (idx >= HWT_SIZE) return;
    int k = idx >> 8;
    int j = idx & 255;
    hWT[idx] = hW[j * 1024 + k];
}

// gi = x . Wih^T for the 3 long encoders, all timesteps, split-bf16 MFMA.
// Output layout (lane-specialized for the recurrence):
//   gi[enc][tile16][t256][wv8][lg4][lr16][c2*3+gate][i]   (24 floats per lane)
// Block: 512 thr, M=128 rows (8 t x 16 s), N=256 cols (one third of G3), K=128.
__global__ void __launch_bounds__(512, 2)
gi_gemm(const int* __restrict__ obs_t, const int* __restrict__ look_t,
        const int* __restrict__ inv_t, const float* __restrict__ emb,
        const unsigned short* __restrict__ WB, float* __restrict__ gi) {
    int b = blockIdx.x;
    int nb = b % 3; b /= 3;
    int tc = b % 32; b /= 32;
    int tile = b % 16;
    int enc = b / 16;
    const int* toks = (enc == 0) ? obs_t : (enc == 1) ? look_t : inv_t;

    __shared__ __align__(16) unsigned short Ahi[128][136];
    __shared__ __align__(16) unsigned short Alo[128][136];

    const int tid = threadIdx.x;
    const int l  = tid & 63;
    const int wv = tid >> 6;
    const int lr = l & 15, lg = l >> 4;
    const int wm = wv & 1, wn = wv >> 1;

    // stage A (gathered embeddings), split to hi/lo bf16
#pragma unroll
    for (int c = 0; c < 2; ++c) {
        int chunk = c * 512 + tid;        // 0..1023 = 128 rows x 8 groups
        int r = chunk >> 3, g = chunk & 7;
        int tl = r >> 4, s = r & 15;
        int t = tc * 8 + tl;
        int tok = toks[(tile * TB + s) * SLEN + t];
        const float* e = emb + (size_t)tok * EDIM + g * 16;
        bf16x8 H0, L0, H1, L1;
#pragma unroll
        for (int q = 0; q < 8; ++q) {
            float v = e[q];
            unsigned short h16 = bf16_rne(v);
            H0[q] = (short)h16; L0[q] = (short)bf16_rne(v - bf16_to_f32(h16));
            float v2 = e[8 + q];
            unsigned short h2 = bf16_rne(v2);
            H1[q] = (short)h2;  L1[q] = (short)bf16_rne(v2 - bf16_to_f32(h2));
        }
        *(bf16x8*)(&Ahi[r][g * 16])     = H0;
        *(bf16x8*)(&Ahi[r][g * 16 + 8]) = H1;
        *(bf16x8*)(&Alo[r][g * 16])     = L0;
        *(bf16x8*)(&Alo[r][g * 16 + 8]) = L1;
    }
    __syncthreads();

    f32x4 acc[4][4];
#pragma unroll
    for (int mf = 0; mf < 4; ++mf)
#pragma unroll
        for (int nf = 0; nf < 4; ++nf) acc[mf][nf] = (f32x4){0.f, 0.f, 0.f, 0.f};

#pragma unroll
    for (int ks = 0; ks < 4; ++ks) {
        bf16x8 Ah[4], Al[4];
#pragma unroll
        for (int mf = 0; mf < 4; ++mf) {
            Ah[mf] = *(const bf16x8*)(&Ahi[16 * (4 * wm + mf) + lr][32 * ks + 8 * lg]);
            Al[mf] = *(const bf16x8*)(&Alo[16 * (4 * wm + mf) + lr][32 * ks + 8 * lg]);
        }
#pragma unroll
        for (int nf = 0; nf < 4; ++nf) {
            int nt = nb * 16 + 4 * wn + nf;          // global N-tile 0..47
            int g3 = nt >> 4, cg = nt & 15;
            int slot = (cg >> 3) * 3 + g3;
            const unsigned short* wb = WB + ((size_t)(enc * 12 + ks) * 8 + (cg & 7)) * WV_STRIDE
                                          + slot * 1024 + l * 8;
            bf16x8 Bh = *(const bf16x8*)(wb);
            bf16x8 Bl = *(const bf16x8*)(wb + 512);
#pragma unroll
            for (int mf = 0; mf < 4; ++mf) {
                acc[mf][nf] = __builtin_amdgcn_mfma_f32_16x16x32_bf16(Ah[mf], Bh, acc[mf][nf], 0, 0, 0);
                acc[mf][nf] = __builtin_amdgcn_mfma_f32_16x16x32_bf16(Ah[mf], Bl, acc[mf][nf], 0, 0, 0);
                acc[mf][nf] = __builtin_amdgcn_mfma_f32_16x16x32_bf16(Al[mf], Bh, acc[mf][nf], 0, 0, 0);
            }
        }
    }

    // write in lane-specialized layout
    size_t tile_base = (size_t)(enc * 16 + tile) * 256 * 12288;
#pragma unroll
    for (int mf = 0; mf < 4; ++mf) {
        int t = tc * 8 + 4 * wm + mf;
#pragma unroll
        for (int nf = 0; nf < 4; ++nf) {
            int nt = nb * 16 + 4 * wn + nf;
            int g3 = nt >> 4, cg = nt & 15;
            int wvb = cg & 7, cc2 = cg >> 3;
            size_t addr = tile_base + (size_t)t * 12288
                        + (((size_t)(wvb * 4 + lg) * 16 + lr) * 24)
                        + (cc2 * 3 + g3) * 4;
            *(float4*)(&gi[addr]) = (float4){acc[mf][nf][0], acc[mf][nf][1],
                                             acc[mf][nf][2], acc[mf][nf][3]};
        }
    }
}

// 512 threads = 8 waves. Wave wv owns channels j = 16*wv + 128*c2 + lr (c2=0,1).
__global__ void __launch_bounds__(512, 2)
gru_mfma(const int* __restrict__ obs_t, const int* __restrict__ obs_l,
         const int* __restrict__ look_t, const int* __restrict__ look_l,
         const int* __restrict__ inv_t, const int* __restrict__ inv_l,
         const int* __restrict__ act_t, const int* __restrict__ act_l,
         const float* __restrict__ emb, const float* __restrict__ bih,
         const float* __restrict__ bhh, const unsigned short* __restrict__ WB,
         const float* __restrict__ gi,
         float* __restrict__ state, float* __restrict__ act_out) {
    const int bid = blockIdx.x;
    // XCD-aware mapping: bid%8 ~ XCD. XCD pair {0,1}->enc0, {2,3}->enc1,
    // {4,5}->enc2; act fills XCDs 6,7 plus the leftover slots everywhere.
    const int x = bid & 7, rr = bid >> 3;   // grid = 176 -> rr in 0..21
    int enc, tile, S;
    const int* toks;
    const int* lens;
    if (x < 6 && rr < 8) {
        enc = x >> 1; tile = (x & 1) * 8 + rr; S = SLEN;
        toks = (enc == 0) ? obs_t : (enc == 1) ? look_t : inv_t;
        lens = (enc == 0) ? obs_l : (enc == 1) ? look_l : inv_l;
    } else {
        enc = 3; S = SALEN;
        tile = (x >= 6) ? (rr * 2 + (x - 6)) : (44 + (rr - 8) * 6 + x);
        toks = act_t; lens = act_l;
    }
    const int tid = threadIdx.x;
    const int l  = tid & 63;
    const int wv = tid >> 6;     // 0..7
    const int lr = l & 15;
    const int lg = l >> 4;

    __shared__ __align__(16) unsigned short xh_hi[TB][PADW];
    __shared__ __align__(16) unsigned short xh_lo[TB][PADW];

    // init h region [128,384) to zero
    {
        int m = tid >> 5, c = tid & 31;
#pragma unroll
        for (int q = 0; q < 8; ++q) {
            xh_hi[m][EDIM + 8 * c + q] = 0;
            xh_lo[m][EDIM + 8 * c + q] = 0;
        }
    }

    int maxlen = 1;
    for (int s = 0; s < TB; ++s) {
        int L = lens[tile * TB + s];
        if (L < 1) L = 1;
        if (L > maxlen) maxlen = L;
    }
    int lenm[4];
#pragma unroll
    for (int i = 0; i < 4; ++i) {
        int L = lens[tile * TB + 4 * lg + i];
        lenm[i] = (L < 1) ? 1 : L;
    }

    float bR[2], bZ[2], bIN[2], bHN[2];
#pragma unroll
    for (int c2 = 0; c2 < 2; ++c2) {
        int j = 16 * wv + 128 * c2 + lr;
        bR[c2]  = bih[enc * G3 + j] + bhh[enc * G3 + j];
        bZ[c2]  = bih[enc * G3 + 256 + j] + bhh[enc * G3 + 256 + j];
        bIN[c2] = bih[enc * G3 + 512 + j];
        bHN[c2] = bhh[enc * G3 + 512 + j];
    }

    float hO[2][4];
#pragma unroll
    for (int c2 = 0; c2 < 2; ++c2)
#pragma unroll
        for (int i = 0; i < 4; ++i) hO[c2][i] = 0.f;

    auto stage = [&](int tt) {
        int m = tid >> 5, g = tid & 31;
        int tok = toks[(tile * TB + m) * S + tt];
        const float4 v = *(const float4*)(emb + (size_t)tok * EDIM + g * 4);
        float vv[4] = {v.x, v.y, v.z, v.w};
        bf16x4 H, Lo;
#pragma unroll
        for (int q = 0; q < 4; ++q) {
            unsigned short h16 = bf16_rne(vv[q]);
            H[q]  = (short)h16;
            Lo[q] = (short)bf16_rne(vv[q] - bf16_to_f32(h16));
        }
        *(bf16x4*)(&xh_hi[m][g * 4]) = H;
        *(bf16x4*)(&xh_lo[m][g * 4]) = Lo;
    };

    const unsigned short* WBw = WB + (size_t)enc * (12 * KK_STRIDE)
                                   + wv * WV_STRIDE + l * 8;

    const bool use_gi = (gi != nullptr) && (enc < 3);

    if (use_gi) {
        // ---------- gi path: recurrence streams Whh only ----------
        const float* giL = gi + (size_t)(enc * 16 + tile) * 256 * 12288
                              + ((size_t)(wv * 4 + lg) * 16 + lr) * 24;
        float4 greg[6];
#pragma unroll
        for (int c = 0; c < 6; ++c) greg[c] = *(const float4*)(giL + c * 4);
        __syncthreads();

        for (int t = 0; t < maxlen; ++t) {
            // consume greg (step t) into accumulator init
            f32x4 aR[2], aZ[2], aNX[2], aNH[2];
#pragma unroll
            for (int c2 = 0; c2 < 2; ++c2) {
                float4 gr = greg[c2 * 3 + 0];
                float4 gz = greg[c2 * 3 + 1];
                float4 gn = greg[c2 * 3 + 2];
#pragma unroll
                for (int i = 0; i < 4; ++i) {
                    aR[c2][i]  = bR[c2]  + ((const float*)&gr)[i];
                    aZ[c2][i]  = bZ[c2]  + ((const float*)&gz)[i];
                    aNX[c2][i] = bIN[c2] + ((const float*)&gn)[i];
                    aNH[c2][i] = bHN[c2];
                }
            }
            // prefetch gi for t+1 (lands during MFMA phase)
            if (t + 1 < maxlen) {
                const float* gsrc = giL + (size_t)(t + 1) * 12288;
#pragma unroll
                for (int c = 0; c < 6; ++c) greg[c] = *(const float4*)(gsrc + c * 4);
            }

#pragma unroll 4
            for (int kk = 4; kk < 12; ++kk) {
                const int off = EDIM + 32 * (kk - 4);
                bf16x8 Ahi = *(const bf16x8*)(&xh_hi[lr][off + 8 * lg]);
                bf16x8 Alo = *(const bf16x8*)(&xh_lo[lr][off + 8 * lg]);
                const unsigned short* wb = WBw + (size_t)kk * KK_STRIDE;
#pragma unroll
                for (int c2 = 0; c2 < 2; ++c2) {
                    bf16x8 BhR = *(const bf16x8*)(wb + (c2 * 3 + 0) * 1024);
                    bf16x8 BlR = *(const bf16x8*)(wb + (c2 * 3 + 0) * 1024 + 512);
                    bf16x8 BhZ = *(const bf16x8*)(wb + (c2 * 3 + 1) * 1024);
                    bf16x8 BlZ = *(const bf16x8*)(wb + (c2 * 3 + 1) * 1024 + 512);
                    bf16x8 BhN = *(const bf16x8*)(wb + (c2 * 3 + 2) * 1024);
                    bf16x8 BlN = *(const bf16x8*)(wb + (c2 * 3 + 2) * 1024 + 512);
                    aR[c2]  = __builtin_amdgcn_mfma_f32_16x16x32_bf16(Ahi, BhR, aR[c2], 0, 0, 0);
                    aR[c2]  = __builtin_amdgcn_mfma_f32_16x16x32_bf16(Ahi, BlR, aR[c2], 0, 0, 0);
                    aR[c2]  = __builtin_amdgcn_mfma_f32_16x16x32_bf16(Alo, BhR, aR[c2], 0, 0, 0);
                    aZ[c2]  = __builtin_amdgcn_mfma_f32_16x16x32_bf16(Ahi, BhZ, aZ[c2], 0, 0, 0);
                    aZ[c2]  = __builtin_amdgcn_mfma_f32_16x16x32_bf16(Ahi, BlZ, aZ[c2], 0, 0, 0);
                    aZ[c2]  = __builtin_amdgcn_mfma_f32_16x16x32_bf16(Alo, BhZ, aZ[c2], 0, 0, 0);
                    aNH[c2] = __builtin_amdgcn_mfma_f32_16x16x32_bf16(Ahi, BhN, aNH[c2], 0, 0, 0);
                    aNH[c2] = __builtin_amdgcn_mfma_f32_16x16x32_bf16(Ahi, BlN, aNH[c2], 0, 0, 0);
                    aNH[c2] = __builtin_amdgcn_mfma_f32_16x16x32_bf16(Alo, BhN, aNH[c2], 0, 0, 0);
                }
            }

            __syncthreads();   // all xh reads of this step done

#pragma unroll
            for (int c2 = 0; c2 < 2; ++c2) {
                int j = 16 * wv + 128 * c2 + lr;
#pragma unroll
                for (int i = 0; i < 4; ++i) {
                    int m = 4 * lg + i;
                    float r = 1.f / (1.f + expf(-aR[c2][i]));
                    float z = 1.f / (1.f + expf(-aZ[c2][i]));
                    float n = tanhf(aNX[c2][i] + r * aNH[c2][i]);
                    float hv = (1.f - z) * n + z * hO[c2][i];
                    hv = (t < lenm[i]) ? hv : hO[c2][i];
                    hO[c2][i] = hv;
                    unsigned short h16 = bf16_rne(hv);
                    xh_hi[m][EDIM + j] = h16;
                    xh_lo[m][EDIM + j] = bf16_rne(hv - bf16_to_f32(h16));
                }
            }
            __syncthreads();
        }
    } else {
        // ---------- fallback / act path: full K=384 streaming ----------
        stage(0);
        __syncthreads();

        for (int t = 0; t < maxlen; ++t) {
            f32x4 aR[2], aZ[2], aNX[2], aNH[2];
#pragma unroll
            for (int c2 = 0; c2 < 2; ++c2) {
                aR[c2]  = (f32x4){bR[c2], bR[c2], bR[c2], bR[c2]};
                aZ[c2]  = (f32x4){bZ[c2], bZ[c2], bZ[c2], bZ[c2]};
                aNX[c2] = (f32x4){bIN[c2], bIN[c2], bIN[c2], bIN[c2]};
                aNH[c2] = (f32x4){bHN[c2], bHN[c2], bHN[c2], bHN[c2]};
            }

#pragma unroll 2
            for (int kk = 0; kk < 12; ++kk) {
                const int off = (kk < 4) ? 32 * kk : EDIM + 32 * (kk - 4);
                bf16x8 Ahi = *(const bf16x8*)(&xh_hi[lr][off + 8 * lg]);
                bf16x8 Alo = *(const bf16x8*)(&xh_lo[lr][off + 8 * lg]);
                const unsigned short* wb = WBw + (size_t)kk * KK_STRIDE;
#pragma unroll
                for (int c2 = 0; c2 < 2; ++c2) {
                    bf16x8 BhR = *(const bf16x8*)(wb + (c2 * 3 + 0) * 1024);
                    bf16x8 BlR = *(const bf16x8*)(wb + (c2 * 3 + 0) * 1024 + 512);
                    bf16x8 BhZ = *(const bf16x8*)(wb + (c2 * 3 + 1) * 1024);
                    bf16x8 BlZ = *(const bf16x8*)(wb + (c2 * 3 + 1) * 1024 + 512);
                    bf16x8 BhN = *(const bf16x8*)(wb + (c2 * 3 + 2) * 1024);
                    bf16x8 BlN = *(const bf16x8*)(wb + (c2 * 3 + 2) * 1024 + 512);
                    aR[c2] = __builtin_amdgcn_mfma_f32_16x16x32_bf16(Ahi, BhR, aR[c2], 0, 0, 0);
                    aR[c2] = __builtin_amdgcn_mfma_f32_16x16x32_bf16(Ahi, BlR, aR[c2], 0, 0, 0);
                    aR[c2] = __builtin_amdgcn_mfma_f32_16x16x32_bf16(Alo, BhR, aR[c2], 0, 0, 0);
                    aZ[c2] = __builtin_amdgcn_mfma_f32_16x16x32_bf16(Ahi, BhZ, aZ[c2], 0, 0, 0);
                    aZ[c2] = __builtin_amdgcn_mfma_f32_16x16x32_bf16(Ahi, BlZ, aZ[c2], 0, 0, 0);
                    aZ[c2] = __builtin_amdgcn_mfma_f32_16x16x32_bf16(Alo, BhZ, aZ[c2], 0, 0, 0);
                    if (kk < 4) {
                        aNX[c2] = __builtin_amdgcn_mfma_f32_16x16x32_bf16(Ahi, BhN, aNX[c2], 0, 0, 0);
                        aNX[c2] = __builtin_amdgcn_mfma_f32_16x16x32_bf16(Ahi, BlN, aNX[c2], 0, 0, 0);
                        aNX[c2] = __builtin_amdgcn_mfma_f32_16x16x32_bf16(Alo, BhN, aNX[c2], 0, 0, 0);
                    } else {
                        aNH[c2] = __builtin_amdgcn_mfma_f32_16x16x32_bf16(Ahi, BhN, aNH[c2], 0, 0, 0);
                        aNH[c2] = __builtin_amdgcn_mfma_f32_16x16x32_bf16(Ahi, BlN, aNH[c2], 0, 0, 0);
                        aNH[c2] = __builtin_amdgcn_mfma_f32_16x16x32_bf16(Alo, BhN, aNH[c2], 0, 0, 0);
                    }
                }
            }

            __syncthreads();

#pragma unroll
            for (int c2 = 0; c2 < 2; ++c2) {
                int j = 16 * wv + 128 * c2 + lr;
#pragma unroll
                for (int i = 0; i < 4; ++i) {
                    int m = 4 * lg + i;
                    float r = 1.f / (1.f + expf(-aR[c2][i]));
                    float z = 1.f / (1.f + expf(-aZ[c2][i]));
                    float n = tanhf(aNX[c2][i] + r * aNH[c2][i]);
                    float hv = (1.f - z) * n + z * hO[c2][i];
                    hv = (t < lenm[i]) ? hv : hO[c2][i];
                    hO[c2][i] = hv;
                    unsigned short h16 = bf16_rne(hv);
                    xh_hi[m][EDIM + j] = h16;
                    xh_lo[m][EDIM + j] = bf16_rne(hv - bf16_to_f32(h16));
                }
            }
            if (t + 1 < maxlen) stage(t + 1);
            __syncthreads();
        }
    }

    // outputs: lane owns (m = 4*lg+i, j = 16*wv + 128*c2 + lr)
#pragma unroll
    for (int c2 = 0; c2 < 2; ++c2) {
        int j = 16 * wv + 128 * c2 + lr;
#pragma unroll
        for (int i = 0; i < 4; ++i) {
            int sg = tile * TB + 4 * lg + i;
            if (enc < 3) state[sg * G3 + enc * HDIM + j] = hO[c2][i];
            else         act_out[sg * HDIM + j] = hO[c2][i];
        }
    }
}

__global__ void __launch_bounds__(256)
mlp_kernel(const float* __restrict__ state, const float* __restrict__ act_out,
           const float* __restrict__ hWT, const float* __restrict__ hb,
           const float* __restrict__ sW, const float* __restrict__ sb,
           float* __restrict__ q) {
    int b = blockIdx.x;
    int j = threadIdx.x;
    __shared__ float st[G3];
    __shared__ float ab[ANUM][HDIM];
#pragma unroll
    for (int i = 0; i < 3; ++i) st[i * 256 + j] = state[b * G3 + i * 256 + j];
#pragma unroll
    for (int i = 0; i < ANUM; ++i) ab[i][j] = act_out[(b * ANUM + i) * HDIM + j];
    __syncthreads();

    float accS = 0.f;
#pragma unroll 4
    for (int k = 0; k < G3; ++k) accS += st[k] * hWT[k * HDIM + j];

    float accA[ANUM];
#pragma unroll
    for (int i = 0; i < ANUM; ++i) accA[i] = 0.f;
    for (int k = 0; k < HDIM; ++k) {
        float w = hWT[(G3 + k) * HDIM + j];
#pragma unroll
        for (int i = 0; i < ANUM; ++i) accA[i] += ab[i][k] * w;
    }

    float base = hb[j] + accS;
    float p[ANUM];
#pragma unroll
    for (int i = 0; i < ANUM; ++i) {
        float zz = base + accA[i];
        zz = zz > 0.f ? zz : 0.f;
        p[i] = zz * sW[j];
    }

    __shared__ float wsum[ANUM][4];
#pragma unroll
    for (int i = 0; i < ANUM; ++i) {
        float v = p[i];
        for (int off = 32; off >= 1; off >>= 1) v += __shfl_down(v, off, 64);
        if ((j & 63) == 0) wsum[i][j >> 6] = v;
    }
    __syncthreads();
    if (j < ANUM) q[b * ANUM + j] = wsum[j][0] + wsum[j][1] + wsum[j][2] + wsum[j][3] + sb[0];
}

extern "C" void kernel_launch(void* const* d_in, const int* in_sizes, int n_in,
                              void* d_out, int out_size, void* d_ws, size_t ws_size,
                              hipStream_t stream) {
    const int* obs_t  = (const int*)d_in[0];
    const int* obs_l  = (const int*)d_in[1];
    const int* look_t = (const int*)d_in[2];
    const int* look_l = (const int*)d_in[3];
    const int* inv_t  = (const int*)d_in[4];
    const int* inv_l  = (const int*)d_in[5];
    const int* act_t  = (const int*)d_in[6];
    const int* act_l  = (const int*)d_in[7];
    const float* emb  = (const float*)d_in[8];
    const float* Wih  = (const float*)d_in[9];
    const float* Whh  = (const float*)d_in[10];
    const float* bih  = (const float*)d_in[11];
    const float* bhh  = (const float*)d_in[12];
    const float* hW   = (const float*)d_in[13];
    const float* hb   = (const float*)d_in[14];
    const float* sW   = (const float*)d_in[15];
    const float* sb   = (const float*)d_in[16];

    float* ws    = (float*)d_ws;
    unsigned short* WB = (unsigned short*)d_ws;
    float* hWT   = ws + OFF_HWT;
    float* state = ws + OFF_STATE;
    float* act_o = ws + OFF_ACT;

    const bool use_gi = (ws_size >= WS_NEED);
    float* gi_ptr = use_gi ? (ws + OFF_GI) : nullptr;

    prep_frag<<<(WB_SHORTS / 2 + 255) / 256, 256, 0, stream>>>(Wih, Whh, WB);
    prep_hwt<<<(HWT_SIZE + 255) / 256, 256, 0, stream>>>(hW, hWT);
    if (use_gi)
        gi_gemm<<<4608, 512, 0, stream>>>(obs_t, look_t, inv_t, emb, WB, gi_ptr);
    gru_mfma<<<176, 512, 0, stream>>>(obs_t, obs_l, look_t, look_l, inv_t, inv_l,
                                      act_t, act_l, emb, bih, bhh, WB, gi_ptr,
                                      state, act_o);
    mlp_kernel<<<256, 256, 0, stream>>>(state, act_o, hWT, hb, sW, sb, (float*)d_out);
}

// Round 6
// 2751.767 us; speedup vs baseline: 4.1195x; 1.1039x over previous
//
#include <hip/hip_runtime.h>
#include <math.h>

#define VSZ 32000
#define EDIM 128
#define HDIM 256
#define BSZ 256
#define SLEN 256
#define ANUM 8
#define SALEN 32
#define G3 768
#define TB 16            // sequences per block (one M-tile)
#define PADW 392         // xh row length in shorts (384 + 8 pad)

// WB: split-bf16 weight fragments: [enc4][kk12][wv8][slot6][hi/lo 2][512 shorts]
#define WB_SHORTS (4 * 12 * 8 * 6 * 2 * 512)    // 2,359,296 shorts = 4.72 MB
#define KK_STRIDE (8 * 6 * 2 * 512)             // 49152 shorts per kk
#define WV_STRIDE (6 * 2 * 512)                 // 6144 shorts per wv
#define OFF_HWT   (WB_SHORTS / 2)               // float offset
#define HWT_SIZE  (1024 * HDIM)
#define OFF_STATE (OFF_HWT + HWT_SIZE)
#define OFF_ACT   (OFF_STATE + BSZ * G3)

typedef __attribute__((ext_vector_type(8))) short bf16x8;
typedef __attribute__((ext_vector_type(4))) short bf16x4;
typedef __attribute__((ext_vector_type(4))) float f32x4;

__device__ __forceinline__ unsigned short bf16_rne(float f) {
    unsigned int u = __builtin_bit_cast(unsigned int, f);
    unsigned int r = (u + 0x7FFFu + ((u >> 16) & 1u)) >> 16;
    return (unsigned short)r;
}
__device__ __forceinline__ float bf16_to_f32(unsigned short h) {
    unsigned int u = ((unsigned int)h) << 16;
    return __builtin_bit_cast(float, u);
}

// B-fragment: lane l elem q -> B[k = 32*kk + 8*(l>>4) + q][n], n = 256*g3 + 16*(wv+8*cc2) + (l&15)
__global__ void prep_frag(const float* __restrict__ Wih, const float* __restrict__ Whh,
                          unsigned short* __restrict__ WB) {
    int idx = blockIdx.x * 256 + threadIdx.x;      // < 1,179,648 (hi elements)
    int q = idx & 7;
    int l = (idx >> 3) & 63;
    int rest = idx >> 9;
    int slot = rest % 6; rest /= 6;                // slot = cc2*3 + g3
    int wv = rest & 7;   rest >>= 3;
    int kk = rest % 12;
    int enc = rest / 12;
    int cc2 = slot / 3, g3 = slot % 3;
    int row = 256 * g3 + 16 * (wv + 8 * cc2) + (l & 15);
    int kloc = 8 * (l >> 4) + q;
    float v;
    if (kk < 4) v = Wih[(enc * G3 + row) * EDIM + 32 * kk + kloc];
    else        v = Whh[(enc * G3 + row) * HDIM + 32 * (kk - 4) + kloc];
    unsigned short hi = bf16_rne(v);
    unsigned short lo = bf16_rne(v - bf16_to_f32(hi));
    size_t base = ((((size_t)(enc * 12 + kk) * 8 + wv) * 6 + slot) * 2) * 512 + l * 8 + q;
    WB[base] = hi;
    WB[base + 512] = lo;
}

__global__ void prep_hwt(const float* __restrict__ hW, float* __restrict__ hWT) {
    int idx = blockIdx.x * 256 + threadIdx.x;
    if (idx >= HWT_SIZE) return;
    int k = idx >> 8;
    int j = idx & 255;
    hWT[idx] = hW[j * 1024 + k];
}

// 1024 threads = 16 waves. Wave w owns ONE channel-tile: channels
// j = 16*(w&7) + 128*(w>>3) + lr. 4 waves/SIMD -> deep load pipelining.
__global__ void __launch_bounds__(1024, 1)
gru_mfma(const int* __restrict__ obs_t, const int* __restrict__ obs_l,
         const int* __restrict__ look_t, const int* __restrict__ look_l,
         const int* __restrict__ inv_t, const int* __restrict__ inv_l,
         const int* __restrict__ act_t, const int* __restrict__ act_l,
         const float* __restrict__ emb, const float* __restrict__ bih,
         const float* __restrict__ bhh, const unsigned short* __restrict__ WB,
         float* __restrict__ state, float* __restrict__ act_out) {
    const int bid = blockIdx.x;
    // XCD-aware mapping: bid%8 ~ XCD. XCD pair {0,1}->enc0, {2,3}->enc1,
    // {4,5}->enc2; act fills XCDs 6,7 plus the leftover slots everywhere.
    const int x = bid & 7, rr = bid >> 3;   // grid = 176 -> rr in 0..21
    int enc, tile, S;
    const int* toks;
    const int* lens;
    if (x < 6 && rr < 8) {
        enc = x >> 1; tile = (x & 1) * 8 + rr; S = SLEN;
        toks = (enc == 0) ? obs_t : (enc == 1) ? look_t : inv_t;
        lens = (enc == 0) ? obs_l : (enc == 1) ? look_l : inv_l;
    } else {
        enc = 3; S = SALEN;
        tile = (x >= 6) ? (rr * 2 + (x - 6)) : (44 + (rr - 8) * 6 + x);
        toks = act_t; lens = act_l;
    }
    const int tid = threadIdx.x;
    const int l   = tid & 63;
    const int w   = tid >> 6;     // 0..15
    const int wvb = w & 7;        // WB wv index
    const int c2  = w >> 3;       // slot group
    const int lr  = l & 15;
    const int lg  = l >> 4;
    const int j   = 16 * wvb + 128 * c2 + lr;   // owned channel

    __shared__ __align__(16) unsigned short xh_hi[TB][PADW];
    __shared__ __align__(16) unsigned short xh_lo[TB][PADW];

    // init h region [128,384) to zero (first 512 threads)
    if (tid < 512) {
        int m = tid >> 5, c = tid & 31;
#pragma unroll
        for (int q = 0; q < 8; ++q) {
            xh_hi[m][EDIM + 8 * c + q] = 0;
            xh_lo[m][EDIM + 8 * c + q] = 0;
        }
    }

    int maxlen = 1;
    for (int s = 0; s < TB; ++s) {
        int L = lens[tile * TB + s];
        if (L < 1) L = 1;
        if (L > maxlen) maxlen = L;
    }
    int lenm[4];
#pragma unroll
    for (int i = 0; i < 4; ++i) {
        int L = lens[tile * TB + 4 * lg + i];
        lenm[i] = (L < 1) ? 1 : L;
    }

    const float bR  = bih[enc * G3 + j] + bhh[enc * G3 + j];
    const float bZ  = bih[enc * G3 + 256 + j] + bhh[enc * G3 + 256 + j];
    const float bIN = bih[enc * G3 + 512 + j];
    const float bHN = bhh[enc * G3 + 512 + j];

    float hO[4];
#pragma unroll
    for (int i = 0; i < 4; ++i) hO[i] = 0.f;

    // stage x_t: first 512 threads, each 4 floats of one seq row
    auto stage = [&](int tt) {
        if (tid < 512) {
            int m = tid >> 5, g = tid & 31;
            int tok = toks[(tile * TB + m) * S + tt];
            const float4 v = *(const float4*)(emb + (size_t)tok * EDIM + g * 4);
            float vv[4] = {v.x, v.y, v.z, v.w};
            bf16x4 H, Lo;
#pragma unroll
            for (int q = 0; q < 4; ++q) {
                unsigned short h16 = bf16_rne(vv[q]);
                H[q]  = (short)h16;
                Lo[q] = (short)bf16_rne(vv[q] - bf16_to_f32(h16));
            }
            *(bf16x4*)(&xh_hi[m][g * 4]) = H;
            *(bf16x4*)(&xh_lo[m][g * 4]) = Lo;
        }
    };

    // this wave's fragment base: its wv slice, its c2 slot group
    const unsigned short* WBw = WB + (size_t)enc * (12 * KK_STRIDE)
                                   + wvb * WV_STRIDE + (c2 * 3) * 1024 + l * 8;

    stage(0);
    __syncthreads();

    for (int t = 0; t < maxlen; ++t) {
        f32x4 aR  = (f32x4){bR, bR, bR, bR};
        f32x4 aZ  = (f32x4){bZ, bZ, bZ, bZ};
        f32x4 aNX = (f32x4){bIN, bIN, bIN, bIN};
        f32x4 aNH = (f32x4){bHN, bHN, bHN, bHN};

#pragma unroll 2
        for (int kk = 0; kk < 12; ++kk) {
            const int off = (kk < 4) ? 32 * kk : EDIM + 32 * (kk - 4);
            bf16x8 Ahi = *(const bf16x8*)(&xh_hi[lr][off + 8 * lg]);
            bf16x8 Alo = *(const bf16x8*)(&xh_lo[lr][off + 8 * lg]);
            const unsigned short* wb = WBw + (size_t)kk * KK_STRIDE;
            bf16x8 BhR = *(const bf16x8*)(wb);
            bf16x8 BlR = *(const bf16x8*)(wb + 512);
            bf16x8 BhZ = *(const bf16x8*)(wb + 1024);
            bf16x8 BlZ = *(const bf16x8*)(wb + 1536);
            bf16x8 BhN = *(const bf16x8*)(wb + 2048);
            bf16x8 BlN = *(const bf16x8*)(wb + 2560);
            aR = __builtin_amdgcn_mfma_f32_16x16x32_bf16(Ahi, BhR, aR, 0, 0, 0);
            aR = __builtin_amdgcn_mfma_f32_16x16x32_bf16(Ahi, BlR, aR, 0, 0, 0);
            aR = __builtin_amdgcn_mfma_f32_16x16x32_bf16(Alo, BhR, aR, 0, 0, 0);
            aZ = __builtin_amdgcn_mfma_f32_16x16x32_bf16(Ahi, BhZ, aZ, 0, 0, 0);
            aZ = __builtin_amdgcn_mfma_f32_16x16x32_bf16(Ahi, BlZ, aZ, 0, 0, 0);
            aZ = __builtin_amdgcn_mfma_f32_16x16x32_bf16(Alo, BhZ, aZ, 0, 0, 0);
            if (kk < 4) {
                aNX = __builtin_amdgcn_mfma_f32_16x16x32_bf16(Ahi, BhN, aNX, 0, 0, 0);
                aNX = __builtin_amdgcn_mfma_f32_16x16x32_bf16(Ahi, BlN, aNX, 0, 0, 0);
                aNX = __builtin_amdgcn_mfma_f32_16x16x32_bf16(Alo, BhN, aNX, 0, 0, 0);
            } else {
                aNH = __builtin_amdgcn_mfma_f32_16x16x32_bf16(Ahi, BhN, aNH, 0, 0, 0);
                aNH = __builtin_amdgcn_mfma_f32_16x16x32_bf16(Ahi, BlN, aNH, 0, 0, 0);
                aNH = __builtin_amdgcn_mfma_f32_16x16x32_bf16(Alo, BhN, aNH, 0, 0, 0);
            }
        }

        __syncthreads();   // all xh reads of this step done

        // gates + h update; C layout: row m = 4*lg + i, col = lr
#pragma unroll
        for (int i = 0; i < 4; ++i) {
            int m = 4 * lg + i;
            float r = 1.f / (1.f + expf(-aR[i]));
            float z = 1.f / (1.f + expf(-aZ[i]));
            float n = tanhf(aNX[i] + r * aNH[i]);
            float hv = (1.f - z) * n + z * hO[i];
            hv = (t < lenm[i]) ? hv : hO[i];
            hO[i] = hv;
            unsigned short h16 = bf16_rne(hv);
            xh_hi[m][EDIM + j] = h16;
            xh_lo[m][EDIM + j] = bf16_rne(hv - bf16_to_f32(h16));
        }
        if (t + 1 < maxlen) stage(t + 1);
        __syncthreads();
    }

    // outputs: lane owns (m = 4*lg+i, channel j)
#pragma unroll
    for (int i = 0; i < 4; ++i) {
        int sg = tile * TB + 4 * lg + i;
        if (enc < 3) state[sg * G3 + enc * HDIM + j] = hO[i];
        else         act_out[sg * HDIM + j] = hO[i];
    }
}

__global__ void __launch_bounds__(256)
mlp_kernel(const float* __restrict__ state, const float* __restrict__ act_out,
           const float* __restrict__ hWT, const float* __restrict__ hb,
           const float* __restrict__ sW, const float* __restrict__ sb,
           float* __restrict__ q) {
    int b = blockIdx.x;
    int j = threadIdx.x;
    __shared__ float st[G3];
    __shared__ float ab[ANUM][HDIM];
#pragma unroll
    for (int i = 0; i < 3; ++i) st[i * 256 + j] = state[b * G3 + i * 256 + j];
#pragma unroll
    for (int i = 0; i < ANUM; ++i) ab[i][j] = act_out[(b * ANUM + i) * HDIM + j];
    __syncthreads();

    float accS = 0.f;
#pragma unroll 4
    for (int k = 0; k < G3; ++k) accS += st[k] * hWT[k * HDIM + j];

    float accA[ANUM];
#pragma unroll
    for (int i = 0; i < ANUM; ++i) accA[i] = 0.f;
    for (int k = 0; k < HDIM; ++k) {
        float w = hWT[(G3 + k) * HDIM + j];
#pragma unroll
        for (int i = 0; i < ANUM; ++i) accA[i] += ab[i][k] * w;
    }

    float base = hb[j] + accS;
    float p[ANUM];
#pragma unroll
    for (int i = 0; i < ANUM; ++i) {
        float zz = base + accA[i];
        zz = zz > 0.f ? zz : 0.f;
        p[i] = zz * sW[j];
    }

    __shared__ float wsum[ANUM][4];
#pragma unroll
    for (int i = 0; i < ANUM; ++i) {
        float v = p[i];
        for (int off = 32; off >= 1; off >>= 1) v += __shfl_down(v, off, 64);
        if ((j & 63) == 0) wsum[i][j >> 6] = v;
    }
    __syncthreads();
    if (j < ANUM) q[b * ANUM + j] = wsum[j][0] + wsum[j][1] + wsum[j][2] + wsum[j][3] + sb[0];
}

extern "C" void kernel_launch(void* const* d_in, const int* in_sizes, int n_in,
                              void* d_out, int out_size, void* d_ws, size_t ws_size,
                              hipStream_t stream) {
    const int* obs_t  = (const int*)d_in[0];
    const int* obs_l  = (const int*)d_in[1];
    const int* look_t = (const int*)d_in[2];
    const int* look_l = (const int*)d_in[3];
    const int* inv_t  = (const int*)d_in[4];
    const int* inv_l  = (const int*)d_in[5];
    const int* act_t  = (const int*)d_in[6];
    const int* act_l  = (const int*)d_in[7];
    const float* emb  = (const float*)d_in[8];
    const float* Wih  = (const float*)d_in[9];
    const float* Whh  = (const float*)d_in[10];
    const float* bih  = (const float*)d_in[11];
    const float* bhh  = (const float*)d_in[12];
    const float* hW   = (const float*)d_in[13];
    const float* hb   = (const float*)d_in[14];
    const float* sW   = (const float*)d_in[15];
    const float* sb   = (const float*)d_in[16];

    float* ws    = (float*)d_ws;
    unsigned short* WB = (unsigned short*)d_ws;
    float* hWT   = ws + OFF_HWT;
    float* state = ws + OFF_STATE;
    float* act_o = ws + OFF_ACT;

    prep_frag<<<(WB_SHORTS / 2 + 255) / 256, 256, 0, stream>>>(Wih, Whh, WB);
    prep_hwt<<<(HWT_SIZE + 255) / 256, 256, 0, stream>>>(hW, hWT);
    gru_mfma<<<176, 1024, 0, stream>>>(obs_t, obs_l, look_t, look_l, inv_t, inv_l,
                                       act_t, act_l, emb, bih, bhh, WB,
                                       state, act_o);
    mlp_kernel<<<256, 256, 0, stream>>>(state, act_o, hWT, hb, sW, sb, (float*)d_out);
}

// Round 7
// 1951.778 us; speedup vs baseline: 5.8079x; 1.4099x over previous
//
#include <hip/hip_runtime.h>
#include <math.h>

#define VSZ 32000
#define EDIM 128
#define HDIM 256
#define BSZ 256
#define SLEN 256
#define ANUM 8
#define SALEN 32
#define G3 768
#define TB 16            // sequences per block (one M-tile)
#define PADW 392         // xh row length in shorts (384 + 8 pad)

// WB: split-bf16 weight fragments: [enc4][kk12][wv8][slot6][hi/lo 2][512 shorts]
// slot = c2*3 + gate (gate 0=r,1=z,2=n). Recurrence loads hi for r,z; hi+lo for n.
#define WB_SHORTS (4 * 12 * 8 * 6 * 2 * 512)    // 2,359,296 shorts = 4.72 MB
#define KK_STRIDE (8 * 6 * 2 * 512)             // 49152 shorts per kk
#define WV_STRIDE (6 * 2 * 512)                 // 6144 shorts per wv
#define OFF_HWT   (WB_SHORTS / 2)               // float offset
#define HWT_SIZE  (1024 * HDIM)
#define OFF_STATE (OFF_HWT + HWT_SIZE)
#define OFF_ACT   (OFF_STATE + BSZ * G3)

typedef __attribute__((ext_vector_type(8))) short bf16x8;
typedef __attribute__((ext_vector_type(4))) short bf16x4;
typedef __attribute__((ext_vector_type(4))) float f32x4;

__device__ __forceinline__ unsigned short bf16_rne(float f) {
    unsigned int u = __builtin_bit_cast(unsigned int, f);
    unsigned int r = (u + 0x7FFFu + ((u >> 16) & 1u)) >> 16;
    return (unsigned short)r;
}
__device__ __forceinline__ float bf16_to_f32(unsigned short h) {
    unsigned int u = ((unsigned int)h) << 16;
    return __builtin_bit_cast(float, u);
}

// B-fragment: lane l elem q -> B[k = 32*kk + 8*(l>>4) + q][n], n = 256*g3 + 16*(wv+8*cc2) + (l&15)
__global__ void prep_frag(const float* __restrict__ Wih, const float* __restrict__ Whh,
                          unsigned short* __restrict__ WB) {
    int idx = blockIdx.x * 256 + threadIdx.x;      // < 1,179,648 (hi elements)
    int q = idx & 7;
    int l = (idx >> 3) & 63;
    int rest = idx >> 9;
    int slot = rest % 6; rest /= 6;                // slot = cc2*3 + g3
    int wv = rest & 7;   rest >>= 3;
    int kk = rest % 12;
    int enc = rest / 12;
    int cc2 = slot / 3, g3 = slot % 3;
    int row = 256 * g3 + 16 * (wv + 8 * cc2) + (l & 15);
    int kloc = 8 * (l >> 4) + q;
    float v;
    if (kk < 4) v = Wih[(enc * G3 + row) * EDIM + 32 * kk + kloc];
    else        v = Whh[(enc * G3 + row) * HDIM + 32 * (kk - 4) + kloc];
    unsigned short hi = bf16_rne(v);
    unsigned short lo = bf16_rne(v - bf16_to_f32(hi));
    size_t base = ((((size_t)(enc * 12 + kk) * 8 + wv) * 6 + slot) * 2) * 512 + l * 8 + q;
    WB[base] = hi;
    WB[base + 512] = lo;
}

__global__ void prep_hwt(const float* __restrict__ hW, float* __restrict__ hWT) {
    int idx = blockIdx.x * 256 + threadIdx.x;
    if (idx >= HWT_SIZE) return;
    int k = idx >> 8;
    int j = idx & 255;
    hWT[idx] = hW[j * 1024 + k];
}

// 1024 threads = 16 waves. Wave w owns ONE channel-tile: channels
// j = 16*(w&7) + 128*(w>>3) + lr. 4 waves/SIMD.
// r,z gates: pure-bf16 weights (hi only). n gate: split-bf16 (hi+lo).
__global__ void __launch_bounds__(1024, 1)
gru_mfma(const int* __restrict__ obs_t, const int* __restrict__ obs_l,
         const int* __restrict__ look_t, const int* __restrict__ look_l,
         const int* __restrict__ inv_t, const int* __restrict__ inv_l,
         const int* __restrict__ act_t, const int* __restrict__ act_l,
         const float* __restrict__ emb, const float* __restrict__ bih,
         const float* __restrict__ bhh, const unsigned short* __restrict__ WB,
         float* __restrict__ state, float* __restrict__ act_out) {
    const int bid = blockIdx.x;
    // XCD-aware mapping: bid%8 ~ XCD. XCD pair {0,1}->enc0, {2,3}->enc1,
    // {4,5}->enc2; act fills XCDs 6,7 plus the leftover slots everywhere.
    const int x = bid & 7, rr = bid >> 3;   // grid = 176 -> rr in 0..21
    int enc, tile, S;
    const int* toks;
    const int* lens;
    if (x < 6 && rr < 8) {
        enc = x >> 1; tile = (x & 1) * 8 + rr; S = SLEN;
        toks = (enc == 0) ? obs_t : (enc == 1) ? look_t : inv_t;
        lens = (enc == 0) ? obs_l : (enc == 1) ? look_l : inv_l;
    } else {
        enc = 3; S = SALEN;
        tile = (x >= 6) ? (rr * 2 + (x - 6)) : (44 + (rr - 8) * 6 + x);
        toks = act_t; lens = act_l;
    }
    const int tid = threadIdx.x;
    const int l   = tid & 63;
    const int w   = tid >> 6;     // 0..15
    const int wvb = w & 7;        // WB wv index
    const int c2  = w >> 3;       // slot group
    const int lr  = l & 15;
    const int lg  = l >> 4;
    const int j   = 16 * wvb + 128 * c2 + lr;   // owned channel

    __shared__ __align__(16) unsigned short xh_hi[TB][PADW];
    __shared__ __align__(16) unsigned short xh_lo[TB][PADW];

    // init h region [128,384) to zero (first 512 threads)
    if (tid < 512) {
        int m = tid >> 5, c = tid & 31;
#pragma unroll
        for (int q = 0; q < 8; ++q) {
            xh_hi[m][EDIM + 8 * c + q] = 0;
            xh_lo[m][EDIM + 8 * c + q] = 0;
        }
    }

    int maxlen = 1;
    for (int s = 0; s < TB; ++s) {
        int L = lens[tile * TB + s];
        if (L < 1) L = 1;
        if (L > maxlen) maxlen = L;
    }
    int lenm[4];
#pragma unroll
    for (int i = 0; i < 4; ++i) {
        int L = lens[tile * TB + 4 * lg + i];
        lenm[i] = (L < 1) ? 1 : L;
    }

    const float bR  = bih[enc * G3 + j] + bhh[enc * G3 + j];
    const float bZ  = bih[enc * G3 + 256 + j] + bhh[enc * G3 + 256 + j];
    const float bIN = bih[enc * G3 + 512 + j];
    const float bHN = bhh[enc * G3 + 512 + j];

    float hO[4];
#pragma unroll
    for (int i = 0; i < 4; ++i) hO[i] = 0.f;

    // stage x_t: first 512 threads, each 4 floats of one seq row
    auto stage = [&](int tt) {
        if (tid < 512) {
            int m = tid >> 5, g = tid & 31;
            int tok = toks[(tile * TB + m) * S + tt];
            const float4 v = *(const float4*)(emb + (size_t)tok * EDIM + g * 4);
            float vv[4] = {v.x, v.y, v.z, v.w};
            bf16x4 H, Lo;
#pragma unroll
            for (int q = 0; q < 4; ++q) {
                unsigned short h16 = bf16_rne(vv[q]);
                H[q]  = (short)h16;
                Lo[q] = (short)bf16_rne(vv[q] - bf16_to_f32(h16));
            }
            *(bf16x4*)(&xh_hi[m][g * 4]) = H;
            *(bf16x4*)(&xh_lo[m][g * 4]) = Lo;
        }
    };

    // this wave's fragment base: its wv slice, its c2 slot group
    const unsigned short* WBw = WB + (size_t)enc * (12 * KK_STRIDE)
                                   + wvb * WV_STRIDE + (c2 * 3) * 1024 + l * 8;

    stage(0);
    __syncthreads();

    for (int t = 0; t < maxlen; ++t) {
        f32x4 aR  = (f32x4){bR, bR, bR, bR};
        f32x4 aZ  = (f32x4){bZ, bZ, bZ, bZ};
        f32x4 aNX = (f32x4){bIN, bIN, bIN, bIN};
        f32x4 aNH = (f32x4){bHN, bHN, bHN, bHN};

#pragma unroll 2
        for (int kk = 0; kk < 12; ++kk) {
            const int off = (kk < 4) ? 32 * kk : EDIM + 32 * (kk - 4);
            bf16x8 Ahi = *(const bf16x8*)(&xh_hi[lr][off + 8 * lg]);
            bf16x8 Alo = *(const bf16x8*)(&xh_lo[lr][off + 8 * lg]);
            const unsigned short* wb = WBw + (size_t)kk * KK_STRIDE;
            bf16x8 BhR = *(const bf16x8*)(wb);            // r: hi only
            bf16x8 BhZ = *(const bf16x8*)(wb + 1024);     // z: hi only
            bf16x8 BhN = *(const bf16x8*)(wb + 2048);     // n: hi + lo
            bf16x8 BlN = *(const bf16x8*)(wb + 2560);
            aR = __builtin_amdgcn_mfma_f32_16x16x32_bf16(Ahi, BhR, aR, 0, 0, 0);
            aR = __builtin_amdgcn_mfma_f32_16x16x32_bf16(Alo, BhR, aR, 0, 0, 0);
            aZ = __builtin_amdgcn_mfma_f32_16x16x32_bf16(Ahi, BhZ, aZ, 0, 0, 0);
            aZ = __builtin_amdgcn_mfma_f32_16x16x32_bf16(Alo, BhZ, aZ, 0, 0, 0);
            if (kk < 4) {
                aNX = __builtin_amdgcn_mfma_f32_16x16x32_bf16(Ahi, BhN, aNX, 0, 0, 0);
                aNX = __builtin_amdgcn_mfma_f32_16x16x32_bf16(Ahi, BlN, aNX, 0, 0, 0);
                aNX = __builtin_amdgcn_mfma_f32_16x16x32_bf16(Alo, BhN, aNX, 0, 0, 0);
            } else {
                aNH = __builtin_amdgcn_mfma_f32_16x16x32_bf16(Ahi, BhN, aNH, 0, 0, 0);
                aNH = __builtin_amdgcn_mfma_f32_16x16x32_bf16(Ahi, BlN, aNH, 0, 0, 0);
                aNH = __builtin_amdgcn_mfma_f32_16x16x32_bf16(Alo, BhN, aNH, 0, 0, 0);
            }
        }

        __syncthreads();   // all xh reads of this step done

        // gates + h update; C layout: row m = 4*lg + i, col = lr
#pragma unroll
        for (int i = 0; i < 4; ++i) {
            int m = 4 * lg + i;
            float r = 1.f / (1.f + expf(-aR[i]));
            float z = 1.f / (1.f + expf(-aZ[i]));
            float n = tanhf(aNX[i] + r * aNH[i]);
            float hv = (1.f - z) * n + z * hO[i];
            hv = (t < lenm[i]) ? hv : hO[i];
            hO[i] = hv;
            unsigned short h16 = bf16_rne(hv);
            xh_hi[m][EDIM + j] = h16;
            xh_lo[m][EDIM + j] = bf16_rne(hv - bf16_to_f32(h16));
        }
        if (t + 1 < maxlen) stage(t + 1);
        __syncthreads();
    }

    // outputs: lane owns (m = 4*lg+i, channel j)
#pragma unroll
    for (int i = 0; i < 4; ++i) {
        int sg = tile * TB + 4 * lg + i;
        if (enc < 3) state[sg * G3 + enc * HDIM + j] = hO[i];
        else         act_out[sg * HDIM + j] = hO[i];
    }
}

__global__ void __launch_bounds__(256)
mlp_kernel(const float* __restrict__ state, const float* __restrict__ act_out,
           const float* __restrict__ hWT, const float* __restrict__ hb,
           const float* __restrict__ sW, const float* __restrict__ sb,
           float* __restrict__ q) {
    int b = blockIdx.x;
    int j = threadIdx.x;
    __shared__ float st[G3];
    __shared__ float ab[ANUM][HDIM];
#pragma unroll
    for (int i = 0; i < 3; ++i) st[i * 256 + j] = state[b * G3 + i * 256 + j];
#pragma unroll
    for (int i = 0; i < ANUM; ++i) ab[i][j] = act_out[(b * ANUM + i) * HDIM + j];
    __syncthreads();

    float accS = 0.f;
#pragma unroll 4
    for (int k = 0; k < G3; ++k) accS += st[k] * hWT[k * HDIM + j];

    float accA[ANUM];
#pragma unroll
    for (int i = 0; i < ANUM; ++i) accA[i] = 0.f;
    for (int k = 0; k < HDIM; ++k) {
        float w = hWT[(G3 + k) * HDIM + j];
#pragma unroll
        for (int i = 0; i < ANUM; ++i) accA[i] += ab[i][k] * w;
    }

    float base = hb[j] + accS;
    float p[ANUM];
#pragma unroll
    for (int i = 0; i < ANUM; ++i) {
        float zz = base + accA[i];
        zz = zz > 0.f ? zz : 0.f;
        p[i] = zz * sW[j];
    }

    __shared__ float wsum[ANUM][4];
#pragma unroll
    for (int i = 0; i < ANUM; ++i) {
        float v = p[i];
        for (int off = 32; off >= 1; off >>= 1) v += __shfl_down(v, off, 64);
        if ((j & 63) == 0) wsum[i][j >> 6] = v;
    }
    __syncthreads();
    if (j < ANUM) q[b * ANUM + j] = wsum[j][0] + wsum[j][1] + wsum[j][2] + wsum[j][3] + sb[0];
}

extern "C" void kernel_launch(void* const* d_in, const int* in_sizes, int n_in,
                              void* d_out, int out_size, void* d_ws, size_t ws_size,
                              hipStream_t stream) {
    const int* obs_t  = (const int*)d_in[0];
    const int* obs_l  = (const int*)d_in[1];
    const int* look_t = (const int*)d_in[2];
    const int* look_l = (const int*)d_in[3];
    const int* inv_t  = (const int*)d_in[4];
    const int* inv_l  = (const int*)d_in[5];
    const int* act_t  = (const int*)d_in[6];
    const int* act_l  = (const int*)d_in[7];
    const float* emb  = (const float*)d_in[8];
    const float* Wih  = (const float*)d_in[9];
    const float* Whh  = (const float*)d_in[10];
    const float* bih  = (const float*)d_in[11];
    const float* bhh  = (const float*)d_in[12];
    const float* hW   = (const float*)d_in[13];
    const float* hb   = (const float*)d_in[14];
    const float* sW   = (const float*)d_in[15];
    const float* sb   = (const float*)d_in[16];

    float* ws    = (float*)d_ws;
    unsigned short* WB = (unsigned short*)d_ws;
    float* hWT   = ws + OFF_HWT;
    float* state = ws + OFF_STATE;
    float* act_o = ws + OFF_ACT;

    prep_frag<<<(WB_SHORTS / 2 + 255) / 256, 256, 0, stream>>>(Wih, Whh, WB);
    prep_hwt<<<(HWT_SIZE + 255) / 256, 256, 0, stream>>>(hW, hWT);
    gru_mfma<<<176, 1024, 0, stream>>>(obs_t, obs_l, look_t, look_l, inv_t, inv_l,
                                       act_t, act_l, emb, bih, bhh, WB,
                                       state, act_o);
    mlp_kernel<<<256, 256, 0, stream>>>(state, act_o, hWT, hb, sW, sb, (float*)d_out);
}

// Round 8
// 1880.090 us; speedup vs baseline: 6.0294x; 1.0381x over previous
//
#include <hip/hip_runtime.h>
#include <math.h>

#define VSZ 32000
#define EDIM 128
#define HDIM 256
#define BSZ 256
#define SLEN 256
#define ANUM 8
#define SALEN 32
#define G3 768
#define TB 16            // sequences per block (one M-tile)
#define PADW 392         // xh row length in shorts (384 + 8 pad)

// WB: split-bf16 weight fragments: [enc4][kk12][wv8][slot6][hi/lo 2][512 shorts]
// slot = c2*3 + gate (gate 0=r,1=z,2=n). Loads: hi for r,z; hi+lo for n.
#define WB_SHORTS (4 * 12 * 8 * 6 * 2 * 512)    // 2,359,296 shorts = 4.72 MB
#define KK_STRIDE (8 * 6 * 2 * 512)             // 49152 shorts per kk
#define WV_STRIDE (6 * 2 * 512)                 // 6144 shorts per wv
#define OFF_HWT   (WB_SHORTS / 2)               // float offset
#define HWT_SIZE  (1024 * HDIM)
#define OFF_STATE (OFF_HWT + HWT_SIZE)
#define OFF_ACT   (OFF_STATE + BSZ * G3)
#define OFF_EX    (OFF_ACT + 2048 * HDIM)       // u32 region: [48][2 parity][2 hf][2048]
#define EX_U32    (48 * 2 * 2 * 2048)           // 393,216 u32
#define OFF_FLAG  (OFF_EX + EX_U32)             // 96 u32 flags
#define WS_NEED_SPLIT ((unsigned long long)(OFF_FLAG + 96) * 4ull)

typedef __attribute__((ext_vector_type(8))) short bf16x8;
typedef __attribute__((ext_vector_type(4))) short bf16x4;
typedef __attribute__((ext_vector_type(4))) float f32x4;

__device__ __forceinline__ unsigned short bf16_rne(float f) {
    unsigned int u = __builtin_bit_cast(unsigned int, f);
    unsigned int r = (u + 0x7FFFu + ((u >> 16) & 1u)) >> 16;
    return (unsigned short)r;
}
__device__ __forceinline__ float bf16_to_f32(unsigned short h) {
    unsigned int u = ((unsigned int)h) << 16;
    return __builtin_bit_cast(float, u);
}

__global__ void prep_frag(const float* __restrict__ Wih, const float* __restrict__ Whh,
                          unsigned short* __restrict__ WB) {
    int idx = blockIdx.x * 256 + threadIdx.x;      // < 1,179,648 (hi elements)
    int q = idx & 7;
    int l = (idx >> 3) & 63;
    int rest = idx >> 9;
    int slot = rest % 6; rest /= 6;                // slot = cc2*3 + g3
    int wv = rest & 7;   rest >>= 3;
    int kk = rest % 12;
    int enc = rest / 12;
    int cc2 = slot / 3, g3 = slot % 3;
    int row = 256 * g3 + 16 * (wv + 8 * cc2) + (l & 15);
    int kloc = 8 * (l >> 4) + q;
    float v;
    if (kk < 4) v = Wih[(enc * G3 + row) * EDIM + 32 * kk + kloc];
    else        v = Whh[(enc * G3 + row) * HDIM + 32 * (kk - 4) + kloc];
    unsigned short hi = bf16_rne(v);
    unsigned short lo = bf16_rne(v - bf16_to_f32(hi));
    size_t base = ((((size_t)(enc * 12 + kk) * 8 + wv) * 6 + slot) * 2) * 512 + l * 8 + q;
    WB[base] = hi;
    WB[base + 512] = lo;
}

__global__ void prep_hwt(const float* __restrict__ hW, float* __restrict__ hWT) {
    int idx = blockIdx.x * 256 + threadIdx.x;
    if (idx >= HWT_SIZE) return;
    int k = idx >> 8;
    int j = idx & 255;
    hWT[idx] = hW[j * 1024 + k];
}

__global__ void init_sync(unsigned int* __restrict__ flags) {
    if (threadIdx.x < 96) flags[threadIdx.x] = 0u;
}

// ---------------- split kernel: 96 long (pairs) + 128 act blocks ----------------
// Long: pair (tile, hf=0/1) on same XCD. Each block owns 128 channels.
// 16 waves: p = w&7 channel-tile, kh = w>>3 kk-half (0: kk0..5, 1: kk6..11).
__global__ void __launch_bounds__(1024, 1)
gru_split(const int* __restrict__ obs_t, const int* __restrict__ obs_l,
          const int* __restrict__ look_t, const int* __restrict__ look_l,
          const int* __restrict__ inv_t, const int* __restrict__ inv_l,
          const int* __restrict__ act_t, const int* __restrict__ act_l,
          const float* __restrict__ emb, const float* __restrict__ bih,
          const float* __restrict__ bhh, const unsigned short* __restrict__ WB,
          unsigned int* __restrict__ exbuf, unsigned int* __restrict__ flags,
          float* __restrict__ state, float* __restrict__ act_out) {
    const int bid = blockIdx.x;
    const int x = bid & 7, rr = bid >> 3;   // grid 224 -> rr 0..27
    const int tid = threadIdx.x;
    const int l   = tid & 63;
    const int w   = tid >> 6;     // 0..15
    const int lr  = l & 15;
    const int lg  = l >> 4;

    __shared__ __align__(16) unsigned short xh_hi[TB][PADW];
    __shared__ __align__(16) unsigned short xh_lo[TB][PADW];
    __shared__ __align__(16) float red2[8][3][64][4];   // 24KB partial sums

    if (x < 6 && rr < 16) {
        // ================= LONG encoder, paired-split path =================
        const int enc  = x >> 1;
        const int tile = (x & 1) * 8 + (rr >> 1);
        const int hf   = rr & 1;
        const int tileG = enc * 16 + tile;     // global long-tile id 0..47
        const int* toks = (enc == 0) ? obs_t : (enc == 1) ? look_t : inv_t;
        const int* lens = (enc == 0) ? obs_l : (enc == 1) ? look_l : inv_l;

        const int p  = w & 7;     // channel-tile within half
        const int kh = w >> 3;    // kk-half
        const int j  = 16 * p + 128 * hf + lr;   // owned channel (kh==0)

        // init h region to zero (first 512 threads) ; stage x(0) (last 512)
        if (tid < 512) {
            int m = tid >> 5, c = tid & 31;
#pragma unroll
            for (int q = 0; q < 8; ++q) {
                xh_hi[m][EDIM + 8 * c + q] = 0;
                xh_lo[m][EDIM + 8 * c + q] = 0;
            }
        } else {
            int st = tid - 512;
            int m = st >> 5, g = st & 31;
            int tok = toks[(tile * TB + m) * SLEN + 0];
            const float4 v = *(const float4*)(emb + (size_t)tok * EDIM + g * 4);
            float vv[4] = {v.x, v.y, v.z, v.w};
            bf16x4 H, Lo;
#pragma unroll
            for (int q = 0; q < 4; ++q) {
                unsigned short h16 = bf16_rne(vv[q]);
                H[q]  = (short)h16;
                Lo[q] = (short)bf16_rne(vv[q] - bf16_to_f32(h16));
            }
            *(bf16x4*)(&xh_hi[m][g * 4]) = H;
            *(bf16x4*)(&xh_lo[m][g * 4]) = Lo;
        }

        int maxlen = 1;
        for (int s = 0; s < TB; ++s) {
            int L = lens[tile * TB + s];
            if (L < 1) L = 1;
            if (L > maxlen) maxlen = L;
        }
        int lenm[4];
#pragma unroll
        for (int i = 0; i < 4; ++i) {
            int L = lens[tile * TB + 4 * lg + i];
            lenm[i] = (L < 1) ? 1 : L;
        }

        // biases only on kh==0 (added once)
        const float bR  = kh ? 0.f : (bih[enc * G3 + j] + bhh[enc * G3 + j]);
        const float bZ  = kh ? 0.f : (bih[enc * G3 + 256 + j] + bhh[enc * G3 + 256 + j]);
        const float bIN = kh ? 0.f : bih[enc * G3 + 512 + j];
        const float bHN = kh ? 0.f : bhh[enc * G3 + 512 + j];

        float hO[4];
#pragma unroll
        for (int i = 0; i < 4; ++i) hO[i] = 0.f;

        // wave's fragment base: wv slice p, slot group = hf
        const unsigned short* WBw = WB + (size_t)enc * (12 * KK_STRIDE)
                                       + p * WV_STRIDE + (hf * 3) * 1024 + l * 8;
        unsigned int* fown = flags + tileG * 2 + hf;
        unsigned int* fpar = flags + tileG * 2 + (1 - hf);

        __syncthreads();

        for (int t = 0; t < maxlen; ++t) {
            f32x4 aR  = (f32x4){bR, bR, bR, bR};
            f32x4 aZ  = (f32x4){bZ, bZ, bZ, bZ};
            f32x4 aNX = (f32x4){bIN, bIN, bIN, bIN};
            f32x4 aNH = (f32x4){bHN, bHN, bHN, bHN};

            if (kh == 0) {
#pragma unroll 2
                for (int kk = 0; kk < 6; ++kk) {
                    const int off = (kk < 4) ? 32 * kk : EDIM + 32 * (kk - 4);
                    bf16x8 Ahi = *(const bf16x8*)(&xh_hi[lr][off + 8 * lg]);
                    bf16x8 Alo = *(const bf16x8*)(&xh_lo[lr][off + 8 * lg]);
                    const unsigned short* wb = WBw + (size_t)kk * KK_STRIDE;
                    bf16x8 BhR = *(const bf16x8*)(wb);
                    bf16x8 BhZ = *(const bf16x8*)(wb + 1024);
                    bf16x8 BhN = *(const bf16x8*)(wb + 2048);
                    bf16x8 BlN = *(const bf16x8*)(wb + 2560);
                    aR = __builtin_amdgcn_mfma_f32_16x16x32_bf16(Ahi, BhR, aR, 0, 0, 0);
                    aR = __builtin_amdgcn_mfma_f32_16x16x32_bf16(Alo, BhR, aR, 0, 0, 0);
                    aZ = __builtin_amdgcn_mfma_f32_16x16x32_bf16(Ahi, BhZ, aZ, 0, 0, 0);
                    aZ = __builtin_amdgcn_mfma_f32_16x16x32_bf16(Alo, BhZ, aZ, 0, 0, 0);
                    if (kk < 4) {
                        aNX = __builtin_amdgcn_mfma_f32_16x16x32_bf16(Ahi, BhN, aNX, 0, 0, 0);
                        aNX = __builtin_amdgcn_mfma_f32_16x16x32_bf16(Ahi, BlN, aNX, 0, 0, 0);
                        aNX = __builtin_amdgcn_mfma_f32_16x16x32_bf16(Alo, BhN, aNX, 0, 0, 0);
                    } else {
                        aNH = __builtin_amdgcn_mfma_f32_16x16x32_bf16(Ahi, BhN, aNH, 0, 0, 0);
                        aNH = __builtin_amdgcn_mfma_f32_16x16x32_bf16(Ahi, BlN, aNH, 0, 0, 0);
                        aNH = __builtin_amdgcn_mfma_f32_16x16x32_bf16(Alo, BhN, aNH, 0, 0, 0);
                    }
                }
            } else {
#pragma unroll 2
                for (int kk = 6; kk < 12; ++kk) {
                    const int off = EDIM + 32 * (kk - 4);
                    bf16x8 Ahi = *(const bf16x8*)(&xh_hi[lr][off + 8 * lg]);
                    bf16x8 Alo = *(const bf16x8*)(&xh_lo[lr][off + 8 * lg]);
                    const unsigned short* wb = WBw + (size_t)kk * KK_STRIDE;
                    bf16x8 BhR = *(const bf16x8*)(wb);
                    bf16x8 BhZ = *(const bf16x8*)(wb + 1024);
                    bf16x8 BhN = *(const bf16x8*)(wb + 2048);
                    bf16x8 BlN = *(const bf16x8*)(wb + 2560);
                    aR = __builtin_amdgcn_mfma_f32_16x16x32_bf16(Ahi, BhR, aR, 0, 0, 0);
                    aR = __builtin_amdgcn_mfma_f32_16x16x32_bf16(Alo, BhR, aR, 0, 0, 0);
                    aZ = __builtin_amdgcn_mfma_f32_16x16x32_bf16(Ahi, BhZ, aZ, 0, 0, 0);
                    aZ = __builtin_amdgcn_mfma_f32_16x16x32_bf16(Alo, BhZ, aZ, 0, 0, 0);
                    aNH = __builtin_amdgcn_mfma_f32_16x16x32_bf16(Ahi, BhN, aNH, 0, 0, 0);
                    aNH = __builtin_amdgcn_mfma_f32_16x16x32_bf16(Ahi, BlN, aNH, 0, 0, 0);
                    aNH = __builtin_amdgcn_mfma_f32_16x16x32_bf16(Alo, BhN, aNH, 0, 0, 0);
                }
                // publish partials
                *(f32x4*)(&red2[p][0][l][0]) = aR;
                *(f32x4*)(&red2[p][1][l][0]) = aZ;
                *(f32x4*)(&red2[p][2][l][0]) = aNH;
            }

            __syncthreads();   // partials ready; all xh reads done

            const bool more = (t + 1 < maxlen);
            if (kh == 0) {
                f32x4 rRp = *(const f32x4*)(&red2[p][0][l][0]);
                f32x4 rZp = *(const f32x4*)(&red2[p][1][l][0]);
                f32x4 rNp = *(const f32x4*)(&red2[p][2][l][0]);
                aR += rRp; aZ += rZp; aNH += rNp;
                unsigned int* exw = exbuf + (((size_t)tileG * 2 + (t & 1)) * 2 + hf) * 2048;
#pragma unroll
                for (int i = 0; i < 4; ++i) {
                    int m = 4 * lg + i;
                    float r = 1.f / (1.f + expf(-aR[i]));
                    float z = 1.f / (1.f + expf(-aZ[i]));
                    float n = tanhf(aNX[i] + r * aNH[i]);
                    float hv = (1.f - z) * n + z * hO[i];
                    hv = (t < lenm[i]) ? hv : hO[i];
                    hO[i] = hv;
                    unsigned short h16 = bf16_rne(hv);
                    unsigned short l16 = bf16_rne(hv - bf16_to_f32(h16));
                    xh_hi[m][EDIM + j] = h16;
                    xh_lo[m][EDIM + j] = l16;
                    if (more) {
                        unsigned int pk = ((unsigned int)h16 << 16) | (unsigned int)l16;
                        __hip_atomic_store(exw + m * 128 + 16 * p + lr, pk,
                                           __ATOMIC_RELAXED, __HIP_MEMORY_SCOPE_AGENT);
                    }
                }
            } else if (more) {
                // stage x(t+1)
                int st = tid - 512;
                int m = st >> 5, g = st & 31;
                int tok = toks[(tile * TB + m) * SLEN + (t + 1)];
                const float4 v = *(const float4*)(emb + (size_t)tok * EDIM + g * 4);
                float vv[4] = {v.x, v.y, v.z, v.w};
                bf16x4 H, Lo;
#pragma unroll
                for (int q = 0; q < 4; ++q) {
                    unsigned short h16 = bf16_rne(vv[q]);
                    H[q]  = (short)h16;
                    Lo[q] = (short)bf16_rne(vv[q] - bf16_to_f32(h16));
                }
                *(bf16x4*)(&xh_hi[m][g * 4]) = H;
                *(bf16x4*)(&xh_lo[m][g * 4]) = Lo;
            }

            if (more) {
                __syncthreads();   // ex stores + stage done (vmcnt drained per wave)
                if (tid == 0) {
                    __hip_atomic_store(fown, (unsigned int)(t + 1),
                                       __ATOMIC_RELEASE, __HIP_MEMORY_SCOPE_AGENT);
                    while (__hip_atomic_load(fpar, __ATOMIC_RELAXED,
                                             __HIP_MEMORY_SCOPE_AGENT) < (unsigned int)(t + 1)) {
                        __builtin_amdgcn_s_sleep(2);
                    }
                }
                __syncthreads();   // partner data ready
                const unsigned int* exr = exbuf + (((size_t)tileG * 2 + (t & 1)) * 2 + (1 - hf)) * 2048;
#pragma unroll
                for (int c = 0; c < 2; ++c) {
                    int idx = tid + c * 1024;
                    unsigned int v = __hip_atomic_load(exr + idx, __ATOMIC_RELAXED,
                                                       __HIP_MEMORY_SCOPE_AGENT);
                    int m = idx >> 7, ch = idx & 127;
                    xh_hi[m][EDIM + 128 * (1 - hf) + ch] = (unsigned short)(v >> 16);
                    xh_lo[m][EDIM + 128 * (1 - hf) + ch] = (unsigned short)(v & 0xFFFFu);
                }
                __syncthreads();   // xh complete for next step
            }
        }

        // outputs: kh==0 waves own (m = 4*lg+i, channel j)
        if (kh == 0) {
#pragma unroll
            for (int i = 0; i < 4; ++i) {
                int sg = tile * TB + 4 * lg + i;
                state[sg * G3 + enc * HDIM + j] = hO[i];
            }
        }
    } else {
        // ================= ACT encoder, solo path (round-7 structure) =================
        const int enc = 3;
        int tile;
        if (x >= 6) tile = rr * 2 + (x - 6);
        else        tile = 56 + (rr - 16) * 6 + x;
        const int* toks = act_t;
        const int* lens = act_l;
        const int S = SALEN;

        const int wvb = w & 7;
        const int c2  = w >> 3;
        const int j   = 16 * wvb + 128 * c2 + lr;

        if (tid < 512) {
            int m = tid >> 5, c = tid & 31;
#pragma unroll
            for (int q = 0; q < 8; ++q) {
                xh_hi[m][EDIM + 8 * c + q] = 0;
                xh_lo[m][EDIM + 8 * c + q] = 0;
            }
        }

        int maxlen = 1;
        for (int s = 0; s < TB; ++s) {
            int L = lens[tile * TB + s];
            if (L < 1) L = 1;
            if (L > maxlen) maxlen = L;
        }
        int lenm[4];
#pragma unroll
        for (int i = 0; i < 4; ++i) {
            int L = lens[tile * TB + 4 * lg + i];
            lenm[i] = (L < 1) ? 1 : L;
        }

        const float bR  = bih[enc * G3 + j] + bhh[enc * G3 + j];
        const float bZ  = bih[enc * G3 + 256 + j] + bhh[enc * G3 + 256 + j];
        const float bIN = bih[enc * G3 + 512 + j];
        const float bHN = bhh[enc * G3 + 512 + j];

        float hO[4];
#pragma unroll
        for (int i = 0; i < 4; ++i) hO[i] = 0.f;

        auto stage = [&](int tt) {
            if (tid < 512) {
                int m = tid >> 5, g = tid & 31;
                int tok = toks[(tile * TB + m) * S + tt];
                const float4 v = *(const float4*)(emb + (size_t)tok * EDIM + g * 4);
                float vv[4] = {v.x, v.y, v.z, v.w};
                bf16x4 H, Lo;
#pragma unroll
                for (int q = 0; q < 4; ++q) {
                    unsigned short h16 = bf16_rne(vv[q]);
                    H[q]  = (short)h16;
                    Lo[q] = (short)bf16_rne(vv[q] - bf16_to_f32(h16));
                }
                *(bf16x4*)(&xh_hi[m][g * 4]) = H;
                *(bf16x4*)(&xh_lo[m][g * 4]) = Lo;
            }
        };

        const unsigned short* WBw = WB + (size_t)enc * (12 * KK_STRIDE)
                                       + wvb * WV_STRIDE + (c2 * 3) * 1024 + l * 8;

        stage(0);
        __syncthreads();

        for (int t = 0; t < maxlen; ++t) {
            f32x4 aR  = (f32x4){bR, bR, bR, bR};
            f32x4 aZ  = (f32x4){bZ, bZ, bZ, bZ};
            f32x4 aNX = (f32x4){bIN, bIN, bIN, bIN};
            f32x4 aNH = (f32x4){bHN, bHN, bHN, bHN};

#pragma unroll 2
            for (int kk = 0; kk < 12; ++kk) {
                const int off = (kk < 4) ? 32 * kk : EDIM + 32 * (kk - 4);
                bf16x8 Ahi = *(const bf16x8*)(&xh_hi[lr][off + 8 * lg]);
                bf16x8 Alo = *(const bf16x8*)(&xh_lo[lr][off + 8 * lg]);
                const unsigned short* wb = WBw + (size_t)kk * KK_STRIDE;
                bf16x8 BhR = *(const bf16x8*)(wb);
                bf16x8 BhZ = *(const bf16x8*)(wb + 1024);
                bf16x8 BhN = *(const bf16x8*)(wb + 2048);
                bf16x8 BlN = *(const bf16x8*)(wb + 2560);
                aR = __builtin_amdgcn_mfma_f32_16x16x32_bf16(Ahi, BhR, aR, 0, 0, 0);
                aR = __builtin_amdgcn_mfma_f32_16x16x32_bf16(Alo, BhR, aR, 0, 0, 0);
                aZ = __builtin_amdgcn_mfma_f32_16x16x32_bf16(Ahi, BhZ, aZ, 0, 0, 0);
                aZ = __builtin_amdgcn_mfma_f32_16x16x32_bf16(Alo, BhZ, aZ, 0, 0, 0);
                if (kk < 4) {
                    aNX = __builtin_amdgcn_mfma_f32_16x16x32_bf16(Ahi, BhN, aNX, 0, 0, 0);
                    aNX = __builtin_amdgcn_mfma_f32_16x16x32_bf16(Ahi, BlN, aNX, 0, 0, 0);
                    aNX = __builtin_amdgcn_mfma_f32_16x16x32_bf16(Alo, BhN, aNX, 0, 0, 0);
                } else {
                    aNH = __builtin_amdgcn_mfma_f32_16x16x32_bf16(Ahi, BhN, aNH, 0, 0, 0);
                    aNH = __builtin_amdgcn_mfma_f32_16x16x32_bf16(Ahi, BlN, aNH, 0, 0, 0);
                    aNH = __builtin_amdgcn_mfma_f32_16x16x32_bf16(Alo, BhN, aNH, 0, 0, 0);
                }
            }

            __syncthreads();

#pragma unroll
            for (int i = 0; i < 4; ++i) {
                int m = 4 * lg + i;
                float r = 1.f / (1.f + expf(-aR[i]));
                float z = 1.f / (1.f + expf(-aZ[i]));
                float n = tanhf(aNX[i] + r * aNH[i]);
                float hv = (1.f - z) * n + z * hO[i];
                hv = (t < lenm[i]) ? hv : hO[i];
                hO[i] = hv;
                unsigned short h16 = bf16_rne(hv);
                xh_hi[m][EDIM + j] = h16;
                xh_lo[m][EDIM + j] = bf16_rne(hv - bf16_to_f32(h16));
            }
            if (t + 1 < maxlen) stage(t + 1);
            __syncthreads();
        }

#pragma unroll
        for (int i = 0; i < 4; ++i) {
            int sg = tile * TB + 4 * lg + i;
            act_out[sg * HDIM + j] = hO[i];
        }
    }
}

// ---------------- fallback solo kernel (round-7) ----------------
__global__ void __launch_bounds__(1024, 1)
gru_mfma(const int* __restrict__ obs_t, const int* __restrict__ obs_l,
         const int* __restrict__ look_t, const int* __restrict__ look_l,
         const int* __restrict__ inv_t, const int* __restrict__ inv_l,
         const int* __restrict__ act_t, const int* __restrict__ act_l,
         const float* __restrict__ emb, const float* __restrict__ bih,
         const float* __restrict__ bhh, const unsigned short* __restrict__ WB,
         float* __restrict__ state, float* __restrict__ act_out) {
    const int bid = blockIdx.x;
    const int x = bid & 7, rr = bid >> 3;
    int enc, tile, S;
    const int* toks;
    const int* lens;
    if (x < 6 && rr < 8) {
        enc = x >> 1; tile = (x & 1) * 8 + rr; S = SLEN;
        toks = (enc == 0) ? obs_t : (enc == 1) ? look_t : inv_t;
        lens = (enc == 0) ? obs_l : (enc == 1) ? look_l : inv_l;
    } else {
        enc = 3; S = SALEN;
        tile = (x >= 6) ? (rr * 2 + (x - 6)) : (44 + (rr - 8) * 6 + x);
        toks = act_t; lens = act_l;
    }
    const int tid = threadIdx.x;
    const int l   = tid & 63;
    const int w   = tid >> 6;
    const int wvb = w & 7;
    const int c2  = w >> 3;
    const int lr  = l & 15;
    const int lg  = l >> 4;
    const int j   = 16 * wvb + 128 * c2 + lr;

    __shared__ __align__(16) unsigned short xh_hi[TB][PADW];
    __shared__ __align__(16) unsigned short xh_lo[TB][PADW];

    if (tid < 512) {
        int m = tid >> 5, c = tid & 31;
#pragma unroll
        for (int q = 0; q < 8; ++q) {
            xh_hi[m][EDIM + 8 * c + q] = 0;
            xh_lo[m][EDIM + 8 * c + q] = 0;
        }
    }

    int maxlen = 1;
    for (int s = 0; s < TB; ++s) {
        int L = lens[tile * TB + s];
        if (L < 1) L = 1;
        if (L > maxlen) maxlen = L;
    }
    int lenm[4];
#pragma unroll
    for (int i = 0; i < 4; ++i) {
        int L = lens[tile * TB + 4 * lg + i];
        lenm[i] = (L < 1) ? 1 : L;
    }

    const float bR  = bih[enc * G3 + j] + bhh[enc * G3 + j];
    const float bZ  = bih[enc * G3 + 256 + j] + bhh[enc * G3 + 256 + j];
    const float bIN = bih[enc * G3 + 512 + j];
    const float bHN = bhh[enc * G3 + 512 + j];

    float hO[4];
#pragma unroll
    for (int i = 0; i < 4; ++i) hO[i] = 0.f;

    auto stage = [&](int tt) {
        if (tid < 512) {
            int m = tid >> 5, g = tid & 31;
            int tok = toks[(tile * TB + m) * S + tt];
            const float4 v = *(const float4*)(emb + (size_t)tok * EDIM + g * 4);
            float vv[4] = {v.x, v.y, v.z, v.w};
            bf16x4 H, Lo;
#pragma unroll
            for (int q = 0; q < 4; ++q) {
                unsigned short h16 = bf16_rne(vv[q]);
                H[q]  = (short)h16;
                Lo[q] = (short)bf16_rne(vv[q] - bf16_to_f32(h16));
            }
            *(bf16x4*)(&xh_hi[m][g * 4]) = H;
            *(bf16x4*)(&xh_lo[m][g * 4]) = Lo;
        }
    };

    const unsigned short* WBw = WB + (size_t)enc * (12 * KK_STRIDE)
                                   + wvb * WV_STRIDE + (c2 * 3) * 1024 + l * 8;

    stage(0);
    __syncthreads();

    for (int t = 0; t < maxlen; ++t) {
        f32x4 aR  = (f32x4){bR, bR, bR, bR};
        f32x4 aZ  = (f32x4){bZ, bZ, bZ, bZ};
        f32x4 aNX = (f32x4){bIN, bIN, bIN, bIN};
        f32x4 aNH = (f32x4){bHN, bHN, bHN, bHN};

#pragma unroll 2
        for (int kk = 0; kk < 12; ++kk) {
            const int off = (kk < 4) ? 32 * kk : EDIM + 32 * (kk - 4);
            bf16x8 Ahi = *(const bf16x8*)(&xh_hi[lr][off + 8 * lg]);
            bf16x8 Alo = *(const bf16x8*)(&xh_lo[lr][off + 8 * lg]);
            const unsigned short* wb = WBw + (size_t)kk * KK_STRIDE;
            bf16x8 BhR = *(const bf16x8*)(wb);
            bf16x8 BhZ = *(const bf16x8*)(wb + 1024);
            bf16x8 BhN = *(const bf16x8*)(wb + 2048);
            bf16x8 BlN = *(const bf16x8*)(wb + 2560);
            aR = __builtin_amdgcn_mfma_f32_16x16x32_bf16(Ahi, BhR, aR, 0, 0, 0);
            aR = __builtin_amdgcn_mfma_f32_16x16x32_bf16(Alo, BhR, aR, 0, 0, 0);
            aZ = __builtin_amdgcn_mfma_f32_16x16x32_bf16(Ahi, BhZ, aZ, 0, 0, 0);
            aZ = __builtin_amdgcn_mfma_f32_16x16x32_bf16(Alo, BhZ, aZ, 0, 0, 0);
            if (kk < 4) {
                aNX = __builtin_amdgcn_mfma_f32_16x16x32_bf16(Ahi, BhN, aNX, 0, 0, 0);
                aNX = __builtin_amdgcn_mfma_f32_16x16x32_bf16(Ahi, BlN, aNX, 0, 0, 0);
                aNX = __builtin_amdgcn_mfma_f32_16x16x32_bf16(Alo, BhN, aNX, 0, 0, 0);
            } else {
                aNH = __builtin_amdgcn_mfma_f32_16x16x32_bf16(Ahi, BhN, aNH, 0, 0, 0);
                aNH = __builtin_amdgcn_mfma_f32_16x16x32_bf16(Ahi, BlN, aNH, 0, 0, 0);
                aNH = __builtin_amdgcn_mfma_f32_16x16x32_bf16(Alo, BhN, aNH, 0, 0, 0);
            }
        }

        __syncthreads();

#pragma unroll
        for (int i = 0; i < 4; ++i) {
            int m = 4 * lg + i;
            float r = 1.f / (1.f + expf(-aR[i]));
            float z = 1.f / (1.f + expf(-aZ[i]));
            float n = tanhf(aNX[i] + r * aNH[i]);
            float hv = (1.f - z) * n + z * hO[i];
            hv = (t < lenm[i]) ? hv : hO[i];
            hO[i] = hv;
            unsigned short h16 = bf16_rne(hv);
            xh_hi[m][EDIM + j] = h16;
            xh_lo[m][EDIM + j] = bf16_rne(hv - bf16_to_f32(h16));
        }
        if (t + 1 < maxlen) stage(t + 1);
        __syncthreads();
    }

#pragma unroll
    for (int i = 0; i < 4; ++i) {
        int sg = tile * TB + 4 * lg + i;
        if (enc < 3) state[sg * G3 + enc * HDIM + j] = hO[i];
        else         act_out[sg * HDIM + j] = hO[i];
    }
}

__global__ void __launch_bounds__(256)
mlp_kernel(const float* __restrict__ state, const float* __restrict__ act_out,
           const float* __restrict__ hWT, const float* __restrict__ hb,
           const float* __restrict__ sW, const float* __restrict__ sb,
           float* __restrict__ q) {
    int b = blockIdx.x;
    int j = threadIdx.x;
    __shared__ float st[G3];
    __shared__ float ab[ANUM][HDIM];
#pragma unroll
    for (int i = 0; i < 3; ++i) st[i * 256 + j] = state[b * G3 + i * 256 + j];
#pragma unroll
    for (int i = 0; i < ANUM; ++i) ab[i][j] = act_out[(b * ANUM + i) * HDIM + j];
    __syncthreads();

    float accS = 0.f;
#pragma unroll 4
    for (int k = 0; k < G3; ++k) accS += st[k] * hWT[k * HDIM + j];

    float accA[ANUM];
#pragma unroll
    for (int i = 0; i < ANUM; ++i) accA[i] = 0.f;
    for (int k = 0; k < HDIM; ++k) {
        float w = hWT[(G3 + k) * HDIM + j];
#pragma unroll
        for (int i = 0; i < ANUM; ++i) accA[i] += ab[i][k] * w;
    }

    float base = hb[j] + accS;
    float p[ANUM];
#pragma unroll
    for (int i = 0; i < ANUM; ++i) {
        float zz = base + accA[i];
        zz = zz > 0.f ? zz : 0.f;
        p[i] = zz * sW[j];
    }

    __shared__ float wsum[ANUM][4];
#pragma unroll
    for (int i = 0; i < ANUM; ++i) {
        float v = p[i];
        for (int off = 32; off >= 1; off >>= 1) v += __shfl_down(v, off, 64);
        if ((j & 63) == 0) wsum[i][j >> 6] = v;
    }
    __syncthreads();
    if (j < ANUM) q[b * ANUM + j] = wsum[j][0] + wsum[j][1] + wsum[j][2] + wsum[j][3] + sb[0];
}

extern "C" void kernel_launch(void* const* d_in, const int* in_sizes, int n_in,
                              void* d_out, int out_size, void* d_ws, size_t ws_size,
                              hipStream_t stream) {
    const int* obs_t  = (const int*)d_in[0];
    const int* obs_l  = (const int*)d_in[1];
    const int* look_t = (const int*)d_in[2];
    const int* look_l = (const int*)d_in[3];
    const int* inv_t  = (const int*)d_in[4];
    const int* inv_l  = (const int*)d_in[5];
    const int* act_t  = (const int*)d_in[6];
    const int* act_l  = (const int*)d_in[7];
    const float* emb  = (const float*)d_in[8];
    const float* Wih  = (const float*)d_in[9];
    const float* Whh  = (const float*)d_in[10];
    const float* bih  = (const float*)d_in[11];
    const float* bhh  = (const float*)d_in[12];
    const float* hW   = (const float*)d_in[13];
    const float* hb   = (const float*)d_in[14];
    const float* sW   = (const float*)d_in[15];
    const float* sb   = (const float*)d_in[16];

    float* ws    = (float*)d_ws;
    unsigned short* WB = (unsigned short*)d_ws;
    float* hWT   = ws + OFF_HWT;
    float* state = ws + OFF_STATE;
    float* act_o = ws + OFF_ACT;
    unsigned int* exbuf = (unsigned int*)(ws + OFF_EX);
    unsigned int* flags = (unsigned int*)(ws + OFF_FLAG);

    prep_frag<<<(WB_SHORTS / 2 + 255) / 256, 256, 0, stream>>>(Wih, Whh, WB);
    prep_hwt<<<(HWT_SIZE + 255) / 256, 256, 0, stream>>>(hW, hWT);
    if (ws_size >= WS_NEED_SPLIT) {
        init_sync<<<1, 128, 0, stream>>>(flags);
        gru_split<<<224, 1024, 0, stream>>>(obs_t, obs_l, look_t, look_l, inv_t, inv_l,
                                            act_t, act_l, emb, bih, bhh, WB,
                                            exbuf, flags, state, act_o);
    } else {
        gru_mfma<<<176, 1024, 0, stream>>>(obs_t, obs_l, look_t, look_l, inv_t, inv_l,
                                           act_t, act_l, emb, bih, bhh, WB,
                                           state, act_o);
    }
    mlp_kernel<<<256, 256, 0, stream>>>(state, act_o, hWT, hb, sW, sb, (float*)d_out);
}